// Round 1
// baseline (109979.651 us; speedup 1.0000x reference)
//
#include <hip/hip_runtime.h>
#include <cstdint>
#include <cstddef>

#define Bsz 512
#define Ssz 128
#define Fsz 128
#define Hsz 512
#define NTWO 1024  /* 2H */

typedef __attribute__((ext_vector_type(8))) short short8;
typedef __attribute__((ext_vector_type(4))) float f32x4;
typedef unsigned int u32;
typedef unsigned short u16;

__device__ __forceinline__ float b2f(u16 u){
  union { u32 i; float f; } v; v.i = ((u32)u) << 16; return v.f;
}
__device__ __forceinline__ u16 f2b(float f){
  union { float f; u32 i; } v; v.f = f;
  u32 x = v.i;
  return (u16)((x + 0x7fffu + ((x >> 16) & 1u)) >> 16);
}
__device__ __forceinline__ void g2l16(const void* g, void* l){
  __builtin_amdgcn_global_load_lds((const __attribute__((address_space(1))) u32*)g,
                                   (__attribute__((address_space(3))) u32*)l, 16, 0, 0);
}
__device__ __forceinline__ float ftanh(float x){
  float a = fabsf(x);
  float e = __expf(-2.f*a);
  float t = __fdividef(1.f - e, 1.f + e);
  return copysignf(t, x);
}
__device__ __forceinline__ void vwait(int n){
  switch(n){
    case 0: asm volatile("s_waitcnt vmcnt(0)" ::: "memory"); break;
    case 2: asm volatile("s_waitcnt vmcnt(2)" ::: "memory"); break;
    case 4: asm volatile("s_waitcnt vmcnt(4)" ::: "memory"); break;
    case 6: asm volatile("s_waitcnt vmcnt(6)" ::: "memory"); break;
    default: break;
  }
}

// RK45 (Dormand-Prince) b-coefficients
#define RB1 0.09114583333333333f
#define RB3 0.4492362982929021f
#define RB4 0.6510416666666666f
#define RB5 (-0.3223921568627451f)
#define RB6 0.13095238095238096f
#define MFMA16 __builtin_amdgcn_mfma_f32_16x16x32_bf16

/* ---------------- setup kernels ---------------- */

__global__ void zero_k(float* h, u16* h2, u32* bar){
  int i = blockIdx.x*256 + threadIdx.x;           // grid 2048*256 = 524288
  if (i < Bsz*Hsz) h[i] = 0.f;
  h2[i] = 0;
  if (i < 256) bar[i] = 0u;
}

__global__ void tsm_k(const float* tp, float* tsm){
  int s = blockIdx.x, tid = threadIdx.x;
  __shared__ float red[8];
  float v = tp[(size_t)tid*Ssz + s] + tp[(size_t)(tid + 256)*Ssz + s];
  int wave = tid >> 6, lane = tid & 63;
  for (int o = 32; o; o >>= 1) v += __shfl_down(v, o);
  if (!lane) red[wave] = v;
  __syncthreads();
  if (!tid) tsm[s] = (red[0] + red[1] + red[2] + red[3]) * (1.f/(512.f*72.f));
}

__global__ void sub_k(const float* tsm, float* subs){
  int i = threadIdx.x;
  if (i < Ssz){
    float dtm = (i == 0) ? 0.f : (tsm[i] - tsm[i-1]);
    float de = (dtm > 1e-4f) ? dtm : 0.f;
    subs[i] = de * 0.125f;
  }
}

__global__ void dti_k(const float* tp, float* dti){
  int i = blockIdx.x*256 + threadIdx.x;
  int ss = i & 127;
  dti[i] = ss ? (tp[i] - tp[i-1]) : 0.f;
}

// w1 (512 x 1024) -> w1t_lin[n][k] = w1[k][n]  (n<1024, k<512), plus swizzled copy
__global__ void tr1_k(const float* w1, u16* lin, u16* swz){
  int i = blockIdx.x*256 + threadIdx.x;           // 524288
  int n = i >> 9, k = i & 511;
  u16 v = f2b(w1[(size_t)k*NTWO + n]);
  lin[i] = v;
  swz[(size_t)n*512 + (k ^ ((n&7)<<3))] = v;
}

__global__ void cvt_k(const float* src, u16* dst, int n){
  int i = blockIdx.x*256 + threadIdx.x;
  if (i < n) dst[i] = f2b(src[i]);
}

// w2 (1024 x 512) -> w2t[n][k] = w2[k][n] swizzled (n<512, k<1024)
__global__ void w2t_k(const float* w2, u16* dst){
  int i = blockIdx.x*256 + threadIdx.x;           // 524288
  int n = i >> 10, k = i & 1023;
  dst[(size_t)n*1024 + (k ^ ((n&7)<<3))] = f2b(w2[(size_t)k*Hsz + n]);
}

// whh (1536 x 512) -> swizzled
__global__ void whh_k(const float* whh, u16* dst){
  int i = blockIdx.x*256 + threadIdx.x;           // 786432
  int n = i >> 9, k = i & 511;
  dst[(size_t)n*512 + (k ^ ((n&7)<<3))] = f2b(whh[i]);
}

// wih (1536 x 129) -> wix[n][k] swizzled, k<128
__global__ void wixs_k(const float* wih, u16* dst){
  int i = blockIdx.x*256 + threadIdx.x;           // 196608
  int n = i >> 7, k = i & 127;
  dst[(size_t)n*128 + (k ^ ((n&7)<<3))] = f2b(wih[(size_t)n*129 + k]);
}

__global__ void wdt_k(const float* wih, float* wdt){
  int i = blockIdx.x*256 + threadIdx.x;
  if (i < 1536) wdt[i] = wih[(size_t)i*129 + 128];
}

// vals (B,S,F) f32 -> xs[s][b][f] bf16 swizzled on f by (b&7)
__global__ void xsl_k(const float* vals, u16* dst){
  int i = blockIdx.x*256 + threadIdx.x;           // 8388608
  int p = i & 127;
  int b = (i >> 7) & 511;
  int s = i >> 16;
  int f = p ^ ((b&7)<<3);
  dst[i] = f2b(vals[((size_t)b*Ssz + s)*Fsz + f]);
}

__global__ void u_k(const float* b2v, const u16* w1t, float* u){
  int i = blockIdx.x*256 + threadIdx.x;
  if (i < NTWO){
    float acc = 0.f;
    for (int j = 0; j < Hsz; ++j) acc += b2v[j] * b2f(w1t[(size_t)i*Hsz + j]);
    u[i] = acc;
  }
}

/* --------- Gt = (w2@w1)^T setup GEMM (baseline structure, mode-5 only) --------- */
struct GArgs {
  const u16* A; const u16* Bt;
  int a_rs, b_rs, K, kmask;
  u16* GtOut;
};

__launch_bounds__(256)
__global__ void gemm_k(GArgs g){
  __shared__ __align__(16) u16 lA[2][64*64];
  __shared__ __align__(16) u16 lB[2][32*64];
  const int tid = threadIdx.x;
  const int wave = tid >> 6, lane = tid & 63;
  const int quad = lane >> 4, l16 = lane & 15;
  const int mb = blockIdx.x * 64;
  const int nb = blockIdx.y * 32;
  f32x4 acc0 = {0.f,0.f,0.f,0.f}, acc1 = {0.f,0.f,0.f,0.f};

  const int r0 = tid >> 3,         c0 = (tid & 7) ^ (r0 & 7);
  const int r1 = (256 + tid) >> 3, c1 = (tid & 7) ^ (r1 & 7);

  const int am = wave*16 + l16;
  const int aoff0 = am*64 + (((quad    ) ^ (am & 7)) << 3);
  const int aoff1 = am*64 + (((4 + quad) ^ (am & 7)) << 3);
  const int bn0 = l16, bn1 = 16 + l16;
  const int boff00 = bn0*64 + (((quad    ) ^ (bn0 & 7)) << 3);
  const int boff01 = bn0*64 + (((4 + quad) ^ (bn0 & 7)) << 3);
  const int boff10 = bn1*64 + (((quad    ) ^ (bn1 & 7)) << 3);
  const int boff11 = bn1*64 + (((4 + quad) ^ (bn1 & 7)) << 3);

  const int nkb = g.K >> 6;
  {
    g2l16(g.A  + (size_t)(mb + r0) * g.a_rs + ((c0 << 3)),             &lA[0][tid << 3]);
    g2l16(g.A  + (size_t)(mb + r1) * g.a_rs + ((c1 << 3)),             &lA[0][(256 + tid) << 3]);
    g2l16(g.Bt + (size_t)(nb + r0) * g.b_rs + (((c0 << 3)) & g.kmask), &lB[0][tid << 3]);
  }
  __syncthreads();
  for (int kb = 0; kb < nkb; ++kb){
    int buf = kb & 1;
    if (kb + 1 < nkb){
      int k0 = (kb + 1) << 6, nbuf = buf ^ 1;
      g2l16(g.A  + (size_t)(mb + r0) * g.a_rs + (k0 + (c0 << 3)),             &lA[nbuf][tid << 3]);
      g2l16(g.A  + (size_t)(mb + r1) * g.a_rs + (k0 + (c1 << 3)),             &lA[nbuf][(256 + tid) << 3]);
      g2l16(g.Bt + (size_t)(nb + r0) * g.b_rs + ((k0 + (c0 << 3)) & g.kmask), &lB[nbuf][tid << 3]);
    }
    short8 a0  = *(const short8*)&lA[buf][aoff0];
    short8 a1  = *(const short8*)&lA[buf][aoff1];
    short8 b00 = *(const short8*)&lB[buf][boff00];
    short8 b01 = *(const short8*)&lB[buf][boff01];
    short8 b10 = *(const short8*)&lB[buf][boff10];
    short8 b11 = *(const short8*)&lB[buf][boff11];
    acc0 = MFMA16(a0, b00, acc0, 0, 0, 0);
    acc0 = MFMA16(a1, b01, acc0, 0, 0, 0);
    acc1 = MFMA16(a0, b10, acc1, 0, 0, 0);
    acc1 = MFMA16(a1, b11, acc1, 0, 0, 0);
    __syncthreads();
  }
  #pragma unroll
  for (int cb = 0; cb < 2; ++cb){
    f32x4 a = cb ? acc1 : acc0;
    int n = nb + cb*16 + l16;
    #pragma unroll
    for (int r = 0; r < 4; ++r){
      int m = mb + wave*16 + quad*4 + r;
      // Gt row m (= t-output col), k index n, swizzle baked on k by (m&7)
      g.GtOut[(size_t)m*NTWO + (n ^ ((m&7)<<3))] = f2b(a[r]);
    }
  }
}

/* ---------------- fused persistent kernel ---------------- */

struct FArgs {
  const u16 *Gt, *w1t, *w2t, *whh, *wix, *xs;
  u16 *t, *Ta, *h2;
  float *h, *GI, *GH, *out;
  const float *subs, *dti, *u, *b1, *b2, *bhh, *bih, *wdt, *gamma, *beta;
  u32 *bar;
};

// streamed GEMM: 64 rows x (NT*16) cols, K = nchunks*64, A/B pre-swizzled in global.
template<int NT>
__device__ __forceinline__ void sgemm(
    const u16* Ag, int astr,
    const u16* Bg, int bstr,
    int nchunks, int cmask, int nclamp,
    int tid, int aoff0, int aoff1,
    int b00, int b01, int b10, int b11, int b20, int b21,
    u16 (&sA)[6][4096], u16 (&sB)[3][4096],
    f32x4& A0, f32x4& A1, f32x4& A2)
{
  const int ar0 = tid>>3, ar1 = 32 + (tid>>3);
  const int gq = (tid&7)<<3;
  const int br0c = ar0 > nclamp ? nclamp : ar0;
  const int br1c = ar1 > nclamp ? nclamp : ar1;
  auto stage = [&](int c, int slot){
    g2l16(Ag + (size_t)ar0*astr + c*64 + gq, &sA[slot][tid<<3]);
    g2l16(Ag + (size_t)ar1*astr + c*64 + gq, &sA[slot][(256+tid)<<3]);
    int cb = (c & cmask)*64;
    g2l16(Bg + (size_t)br0c*bstr + cb + gq, &sB[slot][tid<<3]);
    g2l16(Bg + (size_t)br1c*bstr + cb + gq, &sB[slot][(256+tid)<<3]);
  };
  stage(0,0);
  if (nchunks > 1) stage(1,1);
  int cur = 0;
  for (int c = 0; c < nchunks; ++c){
    vwait((c+1 < nchunks) ? 4 : 0);
    __builtin_amdgcn_s_barrier();
    if (c+2 < nchunks){
      int nslot = cur + 2 >= 3 ? cur - 1 : cur + 2;
      stage(c+2, nslot);
    }
    const u16* ca = sA[cur];
    const u16* cb = sB[cur];
    short8 a0 = *(const short8*)(ca + aoff0);
    short8 a1 = *(const short8*)(ca + aoff1);
    {
      short8 x0 = *(const short8*)(cb + b00);
      short8 x1 = *(const short8*)(cb + b01);
      A0 = MFMA16(a0, x0, A0, 0, 0, 0);
      A0 = MFMA16(a1, x1, A0, 0, 0, 0);
    }
    if constexpr (NT > 1){
      short8 x0 = *(const short8*)(cb + b10);
      short8 x1 = *(const short8*)(cb + b11);
      A1 = MFMA16(a0, x0, A1, 0, 0, 0);
      A1 = MFMA16(a1, x1, A1, 0, 0, 0);
    }
    if constexpr (NT > 2){
      short8 x0 = *(const short8*)(cb + b20);
      short8 x1 = *(const short8*)(cb + b21);
      A2 = MFMA16(a0, x0, A2, 0, 0, 0);
      A2 = MFMA16(a1, x1, A2, 0, 0, 0);
    }
    cur = cur + 1 >= 3 ? 0 : cur + 1;
  }
  __syncthreads();
}

__launch_bounds__(256, 1)
__global__ void fused_k(FArgs f){
  __shared__ __align__(16) u16 sGt[32*1024];   // 64KB resident Gt tile
  __shared__ __align__(16) u16 sA[6][4096];    // 48KB A ring
  __shared__ __align__(16) u16 sB[3][4096];    // 24KB B ring
  __shared__ float sred[16];

  const int tid = threadIdx.x;
  const int wave = tid >> 6, lane = tid & 63;
  const int quad = lane >> 4, l16 = lane & 15;
  const int bid = blockIdx.x;
  const int g  = bid & 7;        // group (XCD-affine under round-robin heuristic)
  const int jb = bid >> 3;       // 0..31 within group
  const int m0 = g * 64;         // group rows [m0, m0+64)
  const int nb = jb * 32;        // ODE output cols

  u32* bcnt = f.bar + g*32;
  u32 ep = 0;

  const int swz = (l16 & 7) << 3;
  const int arow = wave*16 + l16;
  const int aoff0 = arow*64 + ((quad*8) ^ swz);
  const int aoff1 = arow*64 + ((32 + quad*8) ^ swz);
  // streamed-B fragment offsets (rows nt*16+l16, 64-elem chunk)
  const int sb00 = (l16)*64      + ((quad*8) ^ swz);
  const int sb01 = (l16)*64      + ((32 + quad*8) ^ swz);
  const int sb10 = (16+l16)*64   + ((quad*8) ^ swz);
  const int sb11 = (16+l16)*64   + ((32 + quad*8) ^ swz);
  const int sb20 = (32+l16)*64   + ((quad*8) ^ swz);
  const int sb21 = (32+l16)*64   + ((32 + quad*8) ^ swz);
  // resident Gt fragment offsets (rows l16 / 16+l16, stride 1024)
  const int gt00 = (l16)*1024    + ((quad*8) ^ swz);
  const int gt01 = (l16)*1024    + ((32 + quad*8) ^ swz);
  const int gt10 = (16+l16)*1024 + ((quad*8) ^ swz);
  const int gt11 = (16+l16)*1024 + ((32 + quad*8) ^ swz);

  // per-thread constants reused across all 128 timesteps
  const float uu0 = f.u[nb + l16],  uu1 = f.u[nb + 16 + l16];
  const float bb0 = f.b1[nb + l16], bb1 = f.b1[nb + 16 + l16];
  const int   fcol = jb*16 + l16;
  const float b2u = f.b2[fcol];
  const int   hc0 = jb*48 + l16, hc1 = hc0 + 16, hc2 = hc0 + 32;
  const float bhh0 = f.bhh[hc0], bhh1 = f.bhh[hc1], bhh2 = f.bhh[hc2];
  const float bih0 = f.bih[hc0], bih1 = f.bih[hc1], bih2 = f.bih[hc2];
  const float wdt0 = f.wdt[hc0], wdt1 = f.wdt[hc1], wdt2 = f.wdt[hc2];
  const float gam0 = f.gamma[tid], gam1 = f.gamma[tid + 256];
  const float bet0 = f.beta[tid],  bet1 = f.beta[tid + 256];

  // load resident Gt tile: rows [nb, nb+32) of Gt (pre-swizzled) -> linear copy
  #pragma unroll
  for (int it = 0; it < 16; ++it){
    int idx = it*256 + tid;
    g2l16(f.Gt + ((size_t)(nb + (idx >> 7)) << 10) + ((idx & 127) << 3), &sGt[idx << 3]);
  }
  __syncthreads();

  auto gbar = [&](){
    __syncthreads();
    u32 tgt = (++ep) * 32u;
    if (tid == 0){
      __threadfence();
      __hip_atomic_fetch_add(bcnt, 1u, __ATOMIC_RELAXED, __HIP_MEMORY_SCOPE_AGENT);
      while (__hip_atomic_load(bcnt, __ATOMIC_RELAXED, __HIP_MEMORY_SCOPE_AGENT) < tgt)
        __builtin_amdgcn_s_sleep(2);
      __threadfence();
    }
    __syncthreads();
  };

  auto stT = [&](int c, int buf){
    const int gq = (tid & 7) << 3;
    g2l16(f.t + (size_t)(m0 + (tid >> 3))*1024 + c*64 + gq,      &sA[buf][tid << 3]);
    g2l16(f.t + (size_t)(m0 + 32 + (tid >> 3))*1024 + c*64 + gq, &sA[buf][(256 + tid) << 3]);
  };

  auto ode_gemm = [&](f32x4& A0, f32x4& A1){
    stT(0,0); stT(1,1); stT(2,2); stT(3,3);
    #pragma unroll
    for (int c = 0; c < 16; ++c){
      vwait(c <= 12 ? 6 : 2*(15 - c));
      __builtin_amdgcn_s_barrier();
      if (c + 4 < 16) stT(c + 4, (c + 4) % 6);
      const u16* Ab = sA[c % 6];
      const u16* Gb = sGt + c*64;
      short8 a0  = *(const short8*)(Ab + aoff0);
      short8 a1  = *(const short8*)(Ab + aoff1);
      short8 b00 = *(const short8*)(Gb + gt00);
      short8 b01 = *(const short8*)(Gb + gt01);
      short8 b10 = *(const short8*)(Gb + gt10);
      short8 b11 = *(const short8*)(Gb + gt11);
      A0 = MFMA16(a0, b00, A0, 0, 0, 0);
      A0 = MFMA16(a1, b01, A0, 0, 0, 0);
      A1 = MFMA16(a0, b10, A1, 0, 0, 0);
      A1 = MFMA16(a1, b11, A1, 0, 0, 0);
    }
  };

  for (int s = 0; s < Ssz; ++s){
    const float sub = f.subs[s];
    const bool act = (sub > 0.f);

    if (act){
      f32x4 p0, p1, T0, T1;
      f32x4 q00, q01, q10, q11, q20, q21, q30, q31, q40, q41;

      { // p = h@w1 + b1 ; t = tanh(p) ; Tacc = sub*RB1*t
        f32x4 A0 = {0.f,0.f,0.f,0.f}, A1 = {0.f,0.f,0.f,0.f}, A2 = {0.f,0.f,0.f,0.f};
        sgemm<2>(f.h2 + (size_t)m0*1024, 1024, f.w1t + (size_t)nb*512, 512,
                 16, 7, 31, tid, aoff0, aoff1, sb00, sb01, sb10, sb11, sb20, sb21,
                 sA, sB, A0, A1, A2);
        #pragma unroll
        for (int r = 0; r < 4; ++r){
          int trow = m0 + wave*16 + quad*4 + r;
          int sw = (trow & 7) << 3;
          float v0 = A0[r] + bb0; p0[r] = v0;
          float t0 = ftanh(v0);   T0[r] = sub*RB1*t0;
          f.t[(size_t)trow*1024 + ((nb + l16) ^ sw)] = f2b(t0);
          float v1 = A1[r] + bb1; p1[r] = v1;
          float t1 = ftanh(v1);   T1[r] = sub*RB1*t1;
          f.t[(size_t)trow*1024 + ((nb + 16 + l16) ^ sw)] = f2b(t1);
        }
        gbar();
      }

      auto ode_epi = [&](int st, int wtbf, f32x4& A, f32x4& P, f32x4& T,
                         f32x4& Q0, f32x4& Q1, f32x4& Q2, f32x4& Q3, f32x4& Q4,
                         float uu, int ncol){
        #pragma unroll
        for (int r = 0; r < 4; ++r){
          float qv = A[r] + uu;
          float zs;
          if (st == 1){ Q0[r] = qv; zs = 0.2f*qv; }
          else if (st == 2){ Q1[r] = qv; zs = 0.075f*Q0[r] + 0.225f*qv; }
          else if (st == 3){ Q2[r] = qv;
            zs = (44.f/45.f)*Q0[r] + (-56.f/15.f)*Q1[r] + (32.f/9.f)*qv; }
          else if (st == 4){ Q3[r] = qv;
            zs = 2.9525986892242035f*Q0[r] + (-11.595793324188385f)*Q1[r]
               + 9.822892851699436f*Q2[r] + (-0.2908093278463649f)*qv; }
          else if (st == 5){ Q4[r] = qv;
            zs = 2.8462752525252526f*Q0[r] + (-10.757575757575758f)*Q1[r]
               + 8.906422717743473f*Q2[r] + 0.2784090909090909f*Q3[r]
               + (-0.2735313036020583f)*qv; }
          else {
            zs = RB1*Q0[r] + RB3*Q2[r] + RB4*Q3[r] + RB5*Q4[r] + RB6*qv;
          }
          float tv;
          if (st < 6){
            float z = P[r] + sub*zs;
            tv = ftanh(z);
            if (st >= 2){
              float bn = (st == 2) ? RB3 : (st == 3) ? RB4 : (st == 4) ? RB5 : RB6;
              T[r] += sub*bn*tv;
            }
          } else {
            P[r] += sub*zs;
            tv = ftanh(P[r]);
            T[r] += sub*RB1*tv;
          }
          int trow = m0 + wave*16 + quad*4 + r;
          int sw = (trow & 7) << 3;
          f.t[(size_t)trow*1024 + (ncol ^ sw)] = f2b(tv);
          if (wtbf) f.Ta[(size_t)trow*1024 + (ncol ^ sw)] = f2b(T[r]);
        }
      };

      for (int ssb = 0; ssb < 8; ++ssb){
        for (int st = 1; st <= 6; ++st){
          if (ssb == 7 && st == 6) break;
          f32x4 A0 = {0.f,0.f,0.f,0.f}, A1 = {0.f,0.f,0.f,0.f};
          ode_gemm(A0, A1);
          int wt = (ssb == 7 && st == 5) ? 1 : 0;
          ode_epi(st, wt, A0, p0, T0, q00, q10, q20, q30, q40, uu0, nb + l16);
          ode_epi(st, wt, A1, p1, T1, q01, q11, q21, q31, q41, uu1, nb + 16 + l16);
          gbar();
        }
      }

      { // h += Tacc@w2 + 8*sub*b2 ; update h2 hi/lo
        f32x4 A0 = {0.f,0.f,0.f,0.f}, A1 = {0.f,0.f,0.f,0.f}, A2 = {0.f,0.f,0.f,0.f};
        sgemm<1>(f.Ta + (size_t)m0*1024, 1024, f.w2t + (size_t)(jb*16)*1024, 1024,
                 16, 15, 15, tid, aoff0, aoff1, sb00, sb01, sb10, sb11, sb20, sb21,
                 sA, sB, A0, A1, A2);
        #pragma unroll
        for (int r = 0; r < 4; ++r){
          int m = m0 + wave*16 + quad*4 + r;
          int sw = (m & 7) << 3;
          float hv = f.h[(size_t)m*512 + fcol] + A0[r] + 8.f*sub*b2u;
          f.h[(size_t)m*512 + fcol] = hv;
          u16 hi = f2b(hv);
          f.h2[(size_t)m*1024 + (fcol ^ sw)] = hi;
          f.h2[(size_t)m*1024 + ((512 + fcol) ^ sw)] = f2b(hv - b2f(hi));
        }
        gbar();
      }
    }

    { // GH = h@whh^T + bhh
      f32x4 A0 = {0.f,0.f,0.f,0.f}, A1 = {0.f,0.f,0.f,0.f}, A2 = {0.f,0.f,0.f,0.f};
      sgemm<3>(f.h2 + (size_t)m0*1024, 1024, f.whh + (size_t)(jb*48)*512, 512,
               16, 7, 47, tid, aoff0, aoff1, sb00, sb01, sb10, sb11, sb20, sb21,
               sA, sB, A0, A1, A2);
      #pragma unroll
      for (int r = 0; r < 4; ++r){
        int m = m0 + wave*16 + quad*4 + r;
        size_t base = (size_t)m*1536;
        f.GH[base + hc0] = A0[r] + bhh0;
        f.GH[base + hc1] = A1[r] + bhh1;
        f.GH[base + hc2] = A2[r] + bhh2;
      }
    }
    { // GI = x_s@wih_x^T + dti*wdt + bih
      f32x4 A0 = {0.f,0.f,0.f,0.f}, A1 = {0.f,0.f,0.f,0.f}, A2 = {0.f,0.f,0.f,0.f};
      sgemm<3>(f.xs + ((size_t)s*512 + m0)*128, 128, f.wix + (size_t)(jb*48)*128, 128,
               2, 15, 47, tid, aoff0, aoff1, sb00, sb01, sb10, sb11, sb20, sb21,
               sA, sB, A0, A1, A2);
      #pragma unroll
      for (int r = 0; r < 4; ++r){
        int m = m0 + wave*16 + quad*4 + r;
        float dv = f.dti[(size_t)m*Ssz + s];
        size_t base = (size_t)m*1536;
        f.GI[base + hc0] = A0[r] + bih0 + dv*wdt0;
        f.GI[base + hc1] = A1[r] + bih1 + dv*wdt1;
        f.GI[base + hc2] = A2[r] + bih2 + dv*wdt2;
      }
    }
    gbar();

    // GRU + LayerNorm for rows m0 + 2*jb + {0,1}
    #pragma unroll 1
    for (int rr = 0; rr < 2; ++rr){
      int b = m0 + jb*2 + rr;
      size_t gb = (size_t)b*1536;
      float hn0, hn1;
      {
        int j = tid;
        float gr = f.GI[gb + j] + f.GH[gb + j];
        float gz = f.GI[gb + 512 + j] + f.GH[gb + 512 + j];
        float gnn = f.GI[gb + 1024 + j], ghn = f.GH[gb + 1024 + j];
        float rg = 1.f/(1.f + __expf(-gr));
        float zg = 1.f/(1.f + __expf(-gz));
        float ng = ftanh(gnn + rg*ghn);
        float hv = f.h[(size_t)b*512 + j];
        hn0 = (1.f - zg)*ng + zg*hv;
      }
      {
        int j = tid + 256;
        float gr = f.GI[gb + j] + f.GH[gb + j];
        float gz = f.GI[gb + 512 + j] + f.GH[gb + 512 + j];
        float gnn = f.GI[gb + 1024 + j], ghn = f.GH[gb + 1024 + j];
        float rg = 1.f/(1.f + __expf(-gr));
        float zg = 1.f/(1.f + __expf(-gz));
        float ng = ftanh(gnn + rg*ghn);
        float hv = f.h[(size_t)b*512 + j];
        hn1 = (1.f - zg)*ng + zg*hv;
      }
      f.h[(size_t)b*512 + tid] = hn0;
      f.h[(size_t)b*512 + tid + 256] = hn1;
      int sw = (b & 7) << 3;
      u16 hi0 = f2b(hn0);
      f.h2[(size_t)b*1024 + (tid ^ sw)] = hi0;
      f.h2[(size_t)b*1024 + ((512 + tid) ^ sw)] = f2b(hn0 - b2f(hi0));
      u16 hi1 = f2b(hn1);
      f.h2[(size_t)b*1024 + ((tid + 256) ^ sw)] = hi1;
      f.h2[(size_t)b*1024 + ((768 + tid) ^ sw)] = f2b(hn1 - b2f(hi1));

      float sm = hn0 + hn1;
      for (int o = 32; o; o >>= 1) sm += __shfl_down(sm, o);
      if (!lane) sred[wave] = sm;
      __syncthreads();
      if (!tid) sred[8] = (sred[0] + sred[1] + sred[2] + sred[3]) * (1.f/512.f);
      __syncthreads();
      float mu = sred[8];
      float d0 = hn0 - mu, d1 = hn1 - mu;
      float ss = d0*d0 + d1*d1;
      for (int o = 32; o; o >>= 1) ss += __shfl_down(ss, o);
      if (!lane) sred[wave + 4] = ss;
      __syncthreads();
      if (!tid) sred[9] = (sred[4] + sred[5] + sred[6] + sred[7]) * (1.f/512.f) + 1e-5f;
      __syncthreads();
      float isd = rsqrtf(sred[9]);
      size_t ob = ((size_t)b*Ssz + s)*512;
      f.out[ob + tid]       = d0*isd*gam0 + bet0;
      f.out[ob + tid + 256] = d1*isd*gam1 + bet1;
      __syncthreads();
    }
    gbar();
  }
}

/* ---------------- launcher ---------------- */

extern "C" void kernel_launch(void* const* d_in, const int* in_sizes, int n_in,
                              void* d_out, int out_size, void* d_ws, size_t ws_size,
                              hipStream_t stream){
  (void)in_sizes; (void)n_in; (void)out_size; (void)ws_size;
  const float* tp    = (const float*)d_in[0];
  const float* vals  = (const float*)d_in[1];
  const float* w1    = (const float*)d_in[2];
  const float* b1v   = (const float*)d_in[3];
  const float* w2    = (const float*)d_in[4];
  const float* b2v   = (const float*)d_in[5];
  const float* wih   = (const float*)d_in[6];
  const float* whh   = (const float*)d_in[7];
  const float* bih   = (const float*)d_in[8];
  const float* bhh   = (const float*)d_in[9];
  const float* gamma = (const float*)d_in[10];
  const float* beta  = (const float*)d_in[11];
  float* out = (float*)d_out;

  uint8_t* w = (uint8_t*)d_ws;
  size_t off = 0;
  auto alloc = [&](size_t bytes)->void*{
    void* pp = w + off; off += (bytes + 255) & ~(size_t)255; return pp; };
  float* h       = (float*)alloc((size_t)Bsz*Hsz*4);
  u16*   h2     = (u16*)alloc((size_t)Bsz*NTWO*2);
  u16*   tbuf   = (u16*)alloc((size_t)Bsz*NTWO*2);
  u16*   Ta     = (u16*)alloc((size_t)Bsz*NTWO*2);
  float* GH     = (float*)alloc((size_t)Bsz*1536*4);
  float* GI     = (float*)alloc((size_t)Bsz*1536*4);
  u16*   Gt     = (u16*)alloc((size_t)NTWO*NTWO*2);
  u16*   w1tl   = (u16*)alloc((size_t)NTWO*Hsz*2);
  u16*   w1ts   = (u16*)alloc((size_t)NTWO*Hsz*2);
  u16*   w2bf   = (u16*)alloc((size_t)NTWO*Hsz*2);
  u16*   w2ts   = (u16*)alloc((size_t)Hsz*NTWO*2);
  u16*   whhs   = (u16*)alloc((size_t)1536*Hsz*2);
  u16*   wixs   = (u16*)alloc((size_t)1536*128*2);
  u16*   xs     = (u16*)alloc((size_t)Ssz*Bsz*Fsz*2);
  float* wdt    = (float*)alloc(1536*4);
  float* uvec   = (float*)alloc(NTWO*4);
  float* tsm    = (float*)alloc(Ssz*4);
  float* subs   = (float*)alloc(Ssz*4);
  float* dti    = (float*)alloc((size_t)Bsz*Ssz*4);
  u32*   bar    = (u32*)alloc(1024);

  hipLaunchKernelGGL(zero_k, dim3(2048), dim3(256), 0, stream, h, h2, bar);
  hipLaunchKernelGGL(tsm_k,  dim3(128),  dim3(256), 0, stream, tp, tsm);
  hipLaunchKernelGGL(sub_k,  dim3(1),    dim3(128), 0, stream, tsm, subs);
  hipLaunchKernelGGL(dti_k,  dim3(256),  dim3(256), 0, stream, tp, dti);
  hipLaunchKernelGGL(tr1_k,  dim3(2048), dim3(256), 0, stream, w1, w1tl, w1ts);
  hipLaunchKernelGGL(cvt_k,  dim3(2048), dim3(256), 0, stream, w2, w2bf, NTWO*Hsz);
  hipLaunchKernelGGL(w2t_k,  dim3(2048), dim3(256), 0, stream, w2, w2ts);
  hipLaunchKernelGGL(whh_k,  dim3(3072), dim3(256), 0, stream, whh, whhs);
  hipLaunchKernelGGL(wixs_k, dim3(768),  dim3(256), 0, stream, wih, wixs);
  hipLaunchKernelGGL(wdt_k,  dim3(6),    dim3(256), 0, stream, wih, wdt);
  hipLaunchKernelGGL(xsl_k,  dim3(32768),dim3(256), 0, stream, vals, xs);
  hipLaunchKernelGGL(u_k,    dim3(4),    dim3(256), 0, stream, b2v, w1tl, uvec);
  {
    GArgs g{};
    g.A = w1tl; g.Bt = w2bf; g.a_rs = Hsz; g.b_rs = Hsz; g.K = Hsz;
    g.kmask = 511; g.GtOut = Gt;
    hipLaunchKernelGGL(gemm_k, dim3(16,32), dim3(256), 0, stream, g);
  }

  FArgs fa{};
  fa.Gt = Gt; fa.w1t = w1ts; fa.w2t = w2ts; fa.whh = whhs; fa.wix = wixs; fa.xs = xs;
  fa.t = tbuf; fa.Ta = Ta; fa.h2 = h2;
  fa.h = h; fa.GI = GI; fa.GH = GH; fa.out = out;
  fa.subs = subs; fa.dti = dti; fa.u = uvec; fa.b1 = b1v; fa.b2 = b2v;
  fa.bhh = bhh; fa.bih = bih; fa.wdt = wdt; fa.gamma = gamma; fa.beta = beta;
  fa.bar = bar;

  void* params[] = { (void*)&fa };
  hipError_t e = hipLaunchCooperativeKernel((const void*)fused_k, dim3(256), dim3(256),
                                            params, 0u, stream);
  if (e != hipSuccess){
    // fallback: plain launch (256 blocks on 256 CUs co-reside in practice)
    hipLaunchKernelGGL(fused_k, dim3(256), dim3(256), 0, stream, fa);
  }
}

// Round 2
// 48586.667 us; speedup vs baseline: 2.2636x; 2.2636x over previous
//
#include <hip/hip_runtime.h>
#include <cstdint>
#include <cstddef>

#define Bsz 512
#define Ssz 128
#define Fsz 128
#define Hsz 512
#define NTWO 1024  /* 2H */

typedef __attribute__((ext_vector_type(8))) short short8;
typedef __attribute__((ext_vector_type(4))) float f32x4;
typedef unsigned int u32;
typedef unsigned short u16;

__device__ __forceinline__ float b2f(u16 u){
  union { u32 i; float f; } v; v.i = ((u32)u) << 16; return v.f;
}
__device__ __forceinline__ u16 f2b(float f){
  union { float f; u32 i; } v; v.f = f;
  u32 x = v.i;
  return (u16)((x + 0x7fffu + ((x >> 16) & 1u)) >> 16);
}
// AUX: cache-policy bits. 0 = normal (read-only data). 16 = SC1 → device-scope
// load: bypasses L1/L2, coherent at Infinity Cache (cross-XCD safe).
template<int AUX>
__device__ __forceinline__ void g2l16(const void* g, void* l){
  __builtin_amdgcn_global_load_lds((const __attribute__((address_space(1))) u32*)g,
                                   (__attribute__((address_space(3))) u32*)l, 16, 0, AUX);
}
// device-coherent (agent-scope) relaxed stores: write through to L3; no fences.
__device__ __forceinline__ void st_dev(u16* p, u16 v){
  __hip_atomic_store(p, v, __ATOMIC_RELAXED, __HIP_MEMORY_SCOPE_AGENT);
}
__device__ __forceinline__ void st_devf(float* p, float v){
  __hip_atomic_store(p, v, __ATOMIC_RELAXED, __HIP_MEMORY_SCOPE_AGENT);
}
__device__ __forceinline__ float ftanh(float x){
  float a = fabsf(x);
  float e = __expf(-2.f*a);
  float t = __fdividef(1.f - e, 1.f + e);
  return copysignf(t, x);
}
__device__ __forceinline__ void vwait(int n){
  switch(n){
    case 0: asm volatile("s_waitcnt vmcnt(0)" ::: "memory"); break;
    case 2: asm volatile("s_waitcnt vmcnt(2)" ::: "memory"); break;
    case 4: asm volatile("s_waitcnt vmcnt(4)" ::: "memory"); break;
    case 6: asm volatile("s_waitcnt vmcnt(6)" ::: "memory"); break;
    case 8: asm volatile("s_waitcnt vmcnt(8)" ::: "memory"); break;
    default: break;
  }
}

// RK45 (Dormand-Prince) b-coefficients
#define RB1 0.09114583333333333f
#define RB3 0.4492362982929021f
#define RB4 0.6510416666666666f
#define RB5 (-0.3223921568627451f)
#define RB6 0.13095238095238096f
#define MFMA16 __builtin_amdgcn_mfma_f32_16x16x32_bf16

/* ---------------- setup kernels ---------------- */

__global__ void zero_k(float* h, u16* h2, u32* bar){
  int i = blockIdx.x*256 + threadIdx.x;           // grid 2048*256 = 524288
  if (i < Bsz*Hsz) h[i] = 0.f;
  h2[i] = 0;
  if (i < 256) bar[i] = 0u;
}

__global__ void tsm_k(const float* tp, float* tsm){
  int s = blockIdx.x, tid = threadIdx.x;
  __shared__ float red[8];
  float v = tp[(size_t)tid*Ssz + s] + tp[(size_t)(tid + 256)*Ssz + s];
  int wave = tid >> 6, lane = tid & 63;
  for (int o = 32; o; o >>= 1) v += __shfl_down(v, o);
  if (!lane) red[wave] = v;
  __syncthreads();
  if (!tid) tsm[s] = (red[0] + red[1] + red[2] + red[3]) * (1.f/(512.f*72.f));
}

__global__ void sub_k(const float* tsm, float* subs){
  int i = threadIdx.x;
  if (i < Ssz){
    float dtm = (i == 0) ? 0.f : (tsm[i] - tsm[i-1]);
    float de = (dtm > 1e-4f) ? dtm : 0.f;
    subs[i] = de * 0.125f;
  }
}

__global__ void dti_k(const float* tp, float* dti){
  int i = blockIdx.x*256 + threadIdx.x;
  int ss = i & 127;
  dti[i] = ss ? (tp[i] - tp[i-1]) : 0.f;
}

// w1 (512 x 1024) -> w1t_lin[n][k] = w1[k][n]  (n<1024, k<512), plus swizzled copy
__global__ void tr1_k(const float* w1, u16* lin, u16* swz){
  int i = blockIdx.x*256 + threadIdx.x;           // 524288
  int n = i >> 9, k = i & 511;
  u16 v = f2b(w1[(size_t)k*NTWO + n]);
  lin[i] = v;
  swz[(size_t)n*512 + (k ^ ((n&7)<<3))] = v;
}

__global__ void cvt_k(const float* src, u16* dst, int n){
  int i = blockIdx.x*256 + threadIdx.x;
  if (i < n) dst[i] = f2b(src[i]);
}

// w2 (1024 x 512) -> w2t[n][k] = w2[k][n] swizzled (n<512, k<1024)
__global__ void w2t_k(const float* w2, u16* dst){
  int i = blockIdx.x*256 + threadIdx.x;           // 524288
  int n = i >> 10, k = i & 1023;
  dst[(size_t)n*1024 + (k ^ ((n&7)<<3))] = f2b(w2[(size_t)k*Hsz + n]);
}

// whh (1536 x 512) -> swizzled
__global__ void whh_k(const float* whh, u16* dst){
  int i = blockIdx.x*256 + threadIdx.x;           // 786432
  int n = i >> 9, k = i & 511;
  dst[(size_t)n*512 + (k ^ ((n&7)<<3))] = f2b(whh[i]);
}

// wih (1536 x 129) -> wix[n][k] swizzled, k<128
__global__ void wixs_k(const float* wih, u16* dst){
  int i = blockIdx.x*256 + threadIdx.x;           // 196608
  int n = i >> 7, k = i & 127;
  dst[(size_t)n*128 + (k ^ ((n&7)<<3))] = f2b(wih[(size_t)n*129 + k]);
}

__global__ void wdt_k(const float* wih, float* wdt){
  int i = blockIdx.x*256 + threadIdx.x;
  if (i < 1536) wdt[i] = wih[(size_t)i*129 + 128];
}

// vals (B,S,F) f32 -> xs[s][b][f] bf16 swizzled on f by (b&7)
__global__ void xsl_k(const float* vals, u16* dst){
  int i = blockIdx.x*256 + threadIdx.x;           // 8388608
  int p = i & 127;
  int b = (i >> 7) & 511;
  int s = i >> 16;
  int f = p ^ ((b&7)<<3);
  dst[i] = f2b(vals[((size_t)b*Ssz + s)*Fsz + f]);
}

__global__ void u_k(const float* b2v, const u16* w1t, float* u){
  int i = blockIdx.x*256 + threadIdx.x;
  if (i < NTWO){
    float acc = 0.f;
    for (int j = 0; j < Hsz; ++j) acc += b2v[j] * b2f(w1t[(size_t)i*Hsz + j]);
    u[i] = acc;
  }
}

/* --------- Gt = (w2@w1)^T setup GEMM --------- */
struct GArgs {
  const u16* A; const u16* Bt;
  int a_rs, b_rs, K, kmask;
  u16* GtOut;
};

__launch_bounds__(256)
__global__ void gemm_k(GArgs g){
  __shared__ __align__(16) u16 lA[2][64*64];
  __shared__ __align__(16) u16 lB[2][32*64];
  const int tid = threadIdx.x;
  const int wave = tid >> 6, lane = tid & 63;
  const int quad = lane >> 4, l16 = lane & 15;
  const int mb = blockIdx.x * 64;
  const int nb = blockIdx.y * 32;
  f32x4 acc0 = {0.f,0.f,0.f,0.f}, acc1 = {0.f,0.f,0.f,0.f};

  const int r0 = tid >> 3,         c0 = (tid & 7) ^ (r0 & 7);
  const int r1 = (256 + tid) >> 3, c1 = (tid & 7) ^ (r1 & 7);

  const int am = wave*16 + l16;
  const int aoff0 = am*64 + (((quad    ) ^ (am & 7)) << 3);
  const int aoff1 = am*64 + (((4 + quad) ^ (am & 7)) << 3);
  const int bn0 = l16, bn1 = 16 + l16;
  const int boff00 = bn0*64 + (((quad    ) ^ (bn0 & 7)) << 3);
  const int boff01 = bn0*64 + (((4 + quad) ^ (bn0 & 7)) << 3);
  const int boff10 = bn1*64 + (((quad    ) ^ (bn1 & 7)) << 3);
  const int boff11 = bn1*64 + (((4 + quad) ^ (bn1 & 7)) << 3);

  const int nkb = g.K >> 6;
  {
    g2l16<0>(g.A  + (size_t)(mb + r0) * g.a_rs + ((c0 << 3)),             &lA[0][tid << 3]);
    g2l16<0>(g.A  + (size_t)(mb + r1) * g.a_rs + ((c1 << 3)),             &lA[0][(256 + tid) << 3]);
    g2l16<0>(g.Bt + (size_t)(nb + r0) * g.b_rs + (((c0 << 3)) & g.kmask), &lB[0][tid << 3]);
  }
  __syncthreads();
  for (int kb = 0; kb < nkb; ++kb){
    int buf = kb & 1;
    if (kb + 1 < nkb){
      int k0 = (kb + 1) << 6, nbuf = buf ^ 1;
      g2l16<0>(g.A  + (size_t)(mb + r0) * g.a_rs + (k0 + (c0 << 3)),             &lA[nbuf][tid << 3]);
      g2l16<0>(g.A  + (size_t)(mb + r1) * g.a_rs + (k0 + (c1 << 3)),             &lA[nbuf][(256 + tid) << 3]);
      g2l16<0>(g.Bt + (size_t)(nb + r0) * g.b_rs + ((k0 + (c0 << 3)) & g.kmask), &lB[nbuf][tid << 3]);
    }
    short8 a0  = *(const short8*)&lA[buf][aoff0];
    short8 a1  = *(const short8*)&lA[buf][aoff1];
    short8 b00 = *(const short8*)&lB[buf][boff00];
    short8 b01 = *(const short8*)&lB[buf][boff01];
    short8 b10 = *(const short8*)&lB[buf][boff10];
    short8 b11 = *(const short8*)&lB[buf][boff11];
    acc0 = MFMA16(a0, b00, acc0, 0, 0, 0);
    acc0 = MFMA16(a1, b01, acc0, 0, 0, 0);
    acc1 = MFMA16(a0, b10, acc1, 0, 0, 0);
    acc1 = MFMA16(a1, b11, acc1, 0, 0, 0);
    __syncthreads();
  }
  #pragma unroll
  for (int cb = 0; cb < 2; ++cb){
    f32x4 a = cb ? acc1 : acc0;
    int n = nb + cb*16 + l16;
    #pragma unroll
    for (int r = 0; r < 4; ++r){
      int m = mb + wave*16 + quad*4 + r;
      g.GtOut[(size_t)m*NTWO + (n ^ ((m&7)<<3))] = f2b(a[r]);
    }
  }
}

/* ---------------- fused persistent kernel ---------------- */

struct FArgs {
  const u16 *Gt, *w1t, *w2t, *whh, *wix, *xs;
  u16 *t, *Ta, *h2;           // t is double-buffered: t + buf*Bsz*NTWO
  float *h, *GI, *GH, *out;
  const float *subs, *dti, *u, *b1, *b2, *bhh, *bih, *wdt, *gamma, *beta;
  u32 *bar;
};

// streamed GEMM: 64 rows x (NT*16) cols, K = nchunks*64. A aux = AAUX, B aux = 0.
template<int NT, int AAUX>
__device__ __forceinline__ void sgemm(
    const u16* Ag, int astr,
    const u16* Bg, int bstr,
    int nchunks, int cmask, int nclamp,
    int tid, int aoff0, int aoff1,
    int b00, int b01, int b10, int b11, int b20, int b21,
    u16 (&sA)[6][4096], u16 (&sB)[4][4096],
    f32x4& A0, f32x4& A1, f32x4& A2)
{
  const int ar0 = tid>>3, ar1 = 32 + (tid>>3);
  const int gq = (tid&7)<<3;
  const int br0c = ar0 > nclamp ? nclamp : ar0;
  const int br1c = ar1 > nclamp ? nclamp : ar1;
  auto stage = [&](int c, int slot){
    g2l16<AAUX>(Ag + (size_t)ar0*astr + c*64 + gq, &sA[slot][tid<<3]);
    g2l16<AAUX>(Ag + (size_t)ar1*astr + c*64 + gq, &sA[slot][(256+tid)<<3]);
    int cb = (c & cmask)*64;
    g2l16<0>(Bg + (size_t)br0c*bstr + cb + gq, &sB[slot][tid<<3]);
    g2l16<0>(Bg + (size_t)br1c*bstr + cb + gq, &sB[slot][(256+tid)<<3]);
  };
  stage(0,0);
  if (nchunks > 1) stage(1,1);
  if (nchunks > 2) stage(2,2);
  for (int c = 0; c < nchunks; ++c){
    int rem = nchunks - 1 - c;
    vwait(rem >= 2 ? 8 : 4*rem);
    __builtin_amdgcn_s_barrier();
    if (c + 3 < nchunks) stage(c + 3, (c + 3) & 3);
    const u16* ca = sA[c & 3];
    const u16* cb = sB[c & 3];
    short8 a0 = *(const short8*)(ca + aoff0);
    short8 a1 = *(const short8*)(ca + aoff1);
    {
      short8 x0 = *(const short8*)(cb + b00);
      short8 x1 = *(const short8*)(cb + b01);
      A0 = MFMA16(a0, x0, A0, 0, 0, 0);
      A0 = MFMA16(a1, x1, A0, 0, 0, 0);
    }
    if constexpr (NT > 1){
      short8 x0 = *(const short8*)(cb + b10);
      short8 x1 = *(const short8*)(cb + b11);
      A1 = MFMA16(a0, x0, A1, 0, 0, 0);
      A1 = MFMA16(a1, x1, A1, 0, 0, 0);
    }
    if constexpr (NT > 2){
      short8 x0 = *(const short8*)(cb + b20);
      short8 x1 = *(const short8*)(cb + b21);
      A2 = MFMA16(a0, x0, A2, 0, 0, 0);
      A2 = MFMA16(a1, x1, A2, 0, 0, 0);
    }
  }
  __syncthreads();
}

__launch_bounds__(256, 1)
__global__ void fused_k(FArgs f){
  __shared__ __align__(16) u16 sGt[32*1024];   // 64KB resident Gt tile
  __shared__ __align__(16) u16 sA[6][4096];    // 48KB A ring (also GRU staging)
  __shared__ __align__(16) u16 sB[4][4096];    // 32KB B ring (also h staging)
  __shared__ float sred[16];

  const int tid = threadIdx.x;
  const int wave = tid >> 6, lane = tid & 63;
  const int quad = lane >> 4, l16 = lane & 15;
  const int bid = blockIdx.x;
  const int g  = bid & 7;        // group (XCD-affine heuristic; not relied on)
  const int jb = bid >> 3;       // 0..31 within group
  const int m0 = g * 64;         // group rows [m0, m0+64)
  const int nb = jb * 32;        // ODE output cols

  u32* bcnt = f.bar + g*32;
  u32 ep = 0;

  const int swz = (l16 & 7) << 3;
  const int arow = wave*16 + l16;
  const int aoff0 = arow*64 + ((quad*8) ^ swz);
  const int aoff1 = arow*64 + ((32 + quad*8) ^ swz);
  const int sb00 = (l16)*64      + ((quad*8) ^ swz);
  const int sb01 = (l16)*64      + ((32 + quad*8) ^ swz);
  const int sb10 = (16+l16)*64   + ((quad*8) ^ swz);
  const int sb11 = (16+l16)*64   + ((32 + quad*8) ^ swz);
  const int sb20 = (32+l16)*64   + ((quad*8) ^ swz);
  const int sb21 = (32+l16)*64   + ((32 + quad*8) ^ swz);
  const int gt00 = (l16)*1024    + ((quad*8) ^ swz);
  const int gt01 = (l16)*1024    + ((32 + quad*8) ^ swz);
  const int gt10 = (16+l16)*1024 + ((quad*8) ^ swz);
  const int gt11 = (16+l16)*1024 + ((32 + quad*8) ^ swz);

  // per-thread constants reused across all 128 timesteps
  const float uu0 = f.u[nb + l16],  uu1 = f.u[nb + 16 + l16];
  const float bb0 = f.b1[nb + l16], bb1 = f.b1[nb + 16 + l16];
  const int   fcol = jb*16 + l16;
  const float b2u = f.b2[fcol];
  const int   hc0 = jb*48 + l16, hc1 = hc0 + 16, hc2 = hc0 + 32;
  const float bhh0 = f.bhh[hc0], bhh1 = f.bhh[hc1], bhh2 = f.bhh[hc2];
  const float bih0 = f.bih[hc0], bih1 = f.bih[hc1], bih2 = f.bih[hc2];
  const float wdt0 = f.wdt[hc0], wdt1 = f.wdt[hc1], wdt2 = f.wdt[hc2];
  const float gam0 = f.gamma[tid], gam1 = f.gamma[tid + 256];
  const float bet0 = f.beta[tid],  bet1 = f.beta[tid + 256];
  const int   b0row = m0 + jb*2;   // GRU/LN rows

  // load resident Gt tile (read-only, produced by prior kernel)
  #pragma unroll
  for (int it = 0; it < 16; ++it){
    int idx = it*256 + tid;
    g2l16<0>(f.Gt + ((size_t)(nb + (idx >> 7)) << 10) + ((idx & 127) << 3), &sGt[idx << 3]);
  }
  __syncthreads();

  // fence-free group barrier: stores are device-coherent (sc), so release =
  // vmcnt drain + counter bump; acquire = nothing (loads are device-scope).
  auto gbar = [&](){
    asm volatile("s_waitcnt vmcnt(0)" ::: "memory");
    __syncthreads();
    u32 tgt = (++ep) * 32u;
    if (tid == 0){
      __hip_atomic_fetch_add(bcnt, 1u, __ATOMIC_RELAXED, __HIP_MEMORY_SCOPE_AGENT);
      while (__hip_atomic_load(bcnt, __ATOMIC_RELAXED, __HIP_MEMORY_SCOPE_AGENT) < tgt)
        __builtin_amdgcn_s_sleep(2);
    }
    __syncthreads();
  };

  auto stT = [&](const u16* tb, int c, int buf){
    const int gq = (tid & 7) << 3;
    g2l16<16>(tb + (size_t)(m0 + (tid >> 3))*1024 + c*64 + gq,      &sA[buf][tid << 3]);
    g2l16<16>(tb + (size_t)(m0 + 32 + (tid >> 3))*1024 + c*64 + gq, &sA[buf][(256 + tid) << 3]);
  };

  // ODE GEMM, 5-deep prefetch ring over 6 slots (L3-latency cover)
  auto ode_gemm = [&](const u16* tb, f32x4& A0, f32x4& A1){
    stT(tb,0,0); stT(tb,1,1); stT(tb,2,2); stT(tb,3,3); stT(tb,4,4);
    #pragma unroll
    for (int c = 0; c < 16; ++c){
      vwait(c <= 10 ? 8 : 2*(15 - c));
      __builtin_amdgcn_s_barrier();
      if (c + 5 < 16) stT(tb, c + 5, (c + 5) % 6);
      const u16* Ab = sA[c % 6];
      const u16* Gb = sGt + c*64;
      short8 a0  = *(const short8*)(Ab + aoff0);
      short8 a1  = *(const short8*)(Ab + aoff1);
      short8 b00 = *(const short8*)(Gb + gt00);
      short8 b01 = *(const short8*)(Gb + gt01);
      short8 b10 = *(const short8*)(Gb + gt10);
      short8 b11 = *(const short8*)(Gb + gt11);
      A0 = MFMA16(a0, b00, A0, 0, 0, 0);
      A0 = MFMA16(a1, b01, A0, 0, 0, 0);
      A1 = MFMA16(a0, b10, A1, 0, 0, 0);
      A1 = MFMA16(a1, b11, A1, 0, 0, 0);
    }
  };

  const size_t TSZ = (size_t)Bsz*NTWO;

  for (int s = 0; s < Ssz; ++s){
    const float sub = f.subs[s];
    const bool act = (sub > 0.f);   // uniform across all blocks

    if (act){
      f32x4 p0, p1, T0, T1;
      f32x4 q00, q01, q10, q11, q20, q21, q30, q31, q40, q41;

      { // p = h@w1 + b1 ; t(buf0) = tanh(p) ; Tacc = sub*RB1*t
        f32x4 A0 = {0.f,0.f,0.f,0.f}, A1 = {0.f,0.f,0.f,0.f}, A2 = {0.f,0.f,0.f,0.f};
        sgemm<2,16>(f.h2 + (size_t)m0*1024, 1024, f.w1t + (size_t)nb*512, 512,
                 16, 7, 31, tid, aoff0, aoff1, sb00, sb01, sb10, sb11, sb20, sb21,
                 sA, sB, A0, A1, A2);
        u16* tw = f.t;   // buffer 0
        #pragma unroll
        for (int r = 0; r < 4; ++r){
          int trow = m0 + wave*16 + quad*4 + r;
          int sw = (trow & 7) << 3;
          float v0 = A0[r] + bb0; p0[r] = v0;
          float t0 = ftanh(v0);   T0[r] = sub*RB1*t0;
          st_dev(&tw[(size_t)trow*1024 + ((nb + l16) ^ sw)], f2b(t0));
          float v1 = A1[r] + bb1; p1[r] = v1;
          float t1 = ftanh(v1);   T1[r] = sub*RB1*t1;
          st_dev(&tw[(size_t)trow*1024 + ((nb + 16 + l16) ^ sw)], f2b(t1));
        }
        gbar();
      }

      auto ode_epi = [&](int st, int wtbf, u16* tw, f32x4& A, f32x4& P, f32x4& T,
                         f32x4& Q0, f32x4& Q1, f32x4& Q2, f32x4& Q3, f32x4& Q4,
                         float uu, int ncol){
        #pragma unroll
        for (int r = 0; r < 4; ++r){
          float qv = A[r] + uu;
          float zs;
          if (st == 1){ Q0[r] = qv; zs = 0.2f*qv; }
          else if (st == 2){ Q1[r] = qv; zs = 0.075f*Q0[r] + 0.225f*qv; }
          else if (st == 3){ Q2[r] = qv;
            zs = (44.f/45.f)*Q0[r] + (-56.f/15.f)*Q1[r] + (32.f/9.f)*qv; }
          else if (st == 4){ Q3[r] = qv;
            zs = 2.9525986892242035f*Q0[r] + (-11.595793324188385f)*Q1[r]
               + 9.822892851699436f*Q2[r] + (-0.2908093278463649f)*qv; }
          else if (st == 5){ Q4[r] = qv;
            zs = 2.8462752525252526f*Q0[r] + (-10.757575757575758f)*Q1[r]
               + 8.906422717743473f*Q2[r] + 0.2784090909090909f*Q3[r]
               + (-0.2735313036020583f)*qv; }
          else {
            zs = RB1*Q0[r] + RB3*Q2[r] + RB4*Q3[r] + RB5*Q4[r] + RB6*qv;
          }
          float tv;
          if (st < 6){
            float z = P[r] + sub*zs;
            tv = ftanh(z);
            if (st >= 2){
              float bn = (st == 2) ? RB3 : (st == 3) ? RB4 : (st == 4) ? RB5 : RB6;
              T[r] += sub*bn*tv;
            }
          } else {
            P[r] += sub*zs;
            tv = ftanh(P[r]);
            T[r] += sub*RB1*tv;
          }
          int trow = m0 + wave*16 + quad*4 + r;
          int sw = (trow & 7) << 3;
          st_dev(&tw[(size_t)trow*1024 + (ncol ^ sw)], f2b(tv));
          if (wtbf) st_dev(&f.Ta[(size_t)trow*1024 + (ncol ^ sw)], f2b(T[r]));
        }
      };

      int par = 0;  // t buffer last written
      for (int ssb = 0; ssb < 8; ++ssb){
        for (int st = 1; st <= 6; ++st){
          if (ssb == 7 && st == 6) break;
          f32x4 A0 = {0.f,0.f,0.f,0.f}, A1 = {0.f,0.f,0.f,0.f};
          ode_gemm(f.t + (size_t)par*TSZ, A0, A1);
          u16* tw = f.t + (size_t)(par^1)*TSZ;
          int wt = (ssb == 7 && st == 5) ? 1 : 0;
          ode_epi(st, wt, tw, A0, p0, T0, q00, q10, q20, q30, q40, uu0, nb + l16);
          ode_epi(st, wt, tw, A1, p1, T1, q01, q11, q21, q31, q41, uu1, nb + 16 + l16);
          gbar();
          par ^= 1;
        }
      }

      { // h += Tacc@w2 + 8*sub*b2 ; update h2 hi/lo
        f32x4 A0 = {0.f,0.f,0.f,0.f}, A1 = {0.f,0.f,0.f,0.f}, A2 = {0.f,0.f,0.f,0.f};
        sgemm<1,16>(f.Ta + (size_t)m0*1024, 1024, f.w2t + (size_t)(jb*16)*1024, 1024,
                 16, 15, 15, tid, aoff0, aoff1, sb00, sb01, sb10, sb11, sb20, sb21,
                 sA, sB, A0, A1, A2);
        // stage h[64 rows x 16 cols] (device-scope) into sB[0]
        g2l16<16>(f.h + (size_t)(m0 + (tid >> 2))*512 + jb*16 + (tid & 3)*4,
                  &sB[0][tid << 3]);
        asm volatile("s_waitcnt vmcnt(0)" ::: "memory");
        __syncthreads();
        const float* HS = (const float*)&sB[0][0];
        #pragma unroll
        for (int r = 0; r < 4; ++r){
          int lm = wave*16 + quad*4 + r;
          int m = m0 + lm;
          int sw = (m & 7) << 3;
          float hv = HS[lm*16 + l16] + A0[r] + 8.f*sub*b2u;
          st_devf(&f.h[(size_t)m*512 + fcol], hv);
          u16 hi = f2b(hv);
          st_dev(&f.h2[(size_t)m*1024 + (fcol ^ sw)], hi);
          st_dev(&f.h2[(size_t)m*1024 + ((512 + fcol) ^ sw)], f2b(hv - b2f(hi)));
        }
        gbar();
      }
    }

    { // GH = h@whh^T + bhh
      f32x4 A0 = {0.f,0.f,0.f,0.f}, A1 = {0.f,0.f,0.f,0.f}, A2 = {0.f,0.f,0.f,0.f};
      sgemm<3,16>(f.h2 + (size_t)m0*1024, 1024, f.whh + (size_t)(jb*48)*512, 512,
               16, 7, 47, tid, aoff0, aoff1, sb00, sb01, sb10, sb11, sb20, sb21,
               sA, sB, A0, A1, A2);
      #pragma unroll
      for (int r = 0; r < 4; ++r){
        int m = m0 + wave*16 + quad*4 + r;
        size_t base = (size_t)m*1536;
        st_devf(&f.GH[base + hc0], A0[r] + bhh0);
        st_devf(&f.GH[base + hc1], A1[r] + bhh1);
        st_devf(&f.GH[base + hc2], A2[r] + bhh2);
      }
    }
    { // GI = x_s@wih_x^T + dti*wdt + bih
      f32x4 A0 = {0.f,0.f,0.f,0.f}, A1 = {0.f,0.f,0.f,0.f}, A2 = {0.f,0.f,0.f,0.f};
      sgemm<3,0>(f.xs + ((size_t)s*512 + m0)*128, 128, f.wix + (size_t)(jb*48)*128, 128,
               2, 15, 47, tid, aoff0, aoff1, sb00, sb01, sb10, sb11, sb20, sb21,
               sA, sB, A0, A1, A2);
      #pragma unroll
      for (int r = 0; r < 4; ++r){
        int m = m0 + wave*16 + quad*4 + r;
        float dv = f.dti[(size_t)m*Ssz + s];
        size_t base = (size_t)m*1536;
        st_devf(&f.GI[base + hc0], A0[r] + bih0 + dv*wdt0);
        st_devf(&f.GI[base + hc1], A1[r] + bih1 + dv*wdt1);
        st_devf(&f.GI[base + hc2], A2[r] + bih2 + dv*wdt2);
      }
    }
    gbar();

    // ---- GRU + LayerNorm for rows b0row, b0row+1 ----
    // stage GI/GH (2 rows x 1536 f32 x 2 bufs = 24 KB) + h (2x512 f32 = 4 KB)
    {
      float* LS = (float*)&sA[0][0];
      #pragma unroll
      for (int k2 = 0; k2 < 6; ++k2){
        int idx = k2*256 + tid;        // 0..1535
        int row = idx >> 9 >= 0 ? (idx / 768) : 0;
        int rem = idx - row*768;
        int buf = rem / 384;
        int goff = rem - buf*384;
        const float* src = (buf ? f.GH : f.GI) + (size_t)(b0row + row)*1536 + goff*4;
        g2l16<16>(src, (char*)LS + (size_t)idx*16);
      }
      {
        int row = tid >> 7, off = tid & 127;
        g2l16<16>(f.h + (size_t)(b0row + row)*512 + off*4,
                  (char*)LS + (size_t)(1536 + tid)*16);
      }
      asm volatile("s_waitcnt vmcnt(0)" ::: "memory");
      __syncthreads();

      #pragma unroll 1
      for (int rr = 0; rr < 2; ++rr){
        int b = b0row + rr;
        const float* GIr = LS + rr*3072;
        const float* GHr = LS + rr*3072 + 1536;
        const float* Hr  = LS + 6144 + rr*512;
        float hn0, hn1;
        {
          int j = tid;
          float gr = GIr[j] + GHr[j];
          float gz = GIr[512 + j] + GHr[512 + j];
          float gnn = GIr[1024 + j], ghn = GHr[1024 + j];
          float rg = 1.f/(1.f + __expf(-gr));
          float zg = 1.f/(1.f + __expf(-gz));
          float ng = ftanh(gnn + rg*ghn);
          hn0 = (1.f - zg)*ng + zg*Hr[j];
        }
        {
          int j = tid + 256;
          float gr = GIr[j] + GHr[j];
          float gz = GIr[512 + j] + GHr[512 + j];
          float gnn = GIr[1024 + j], ghn = GHr[1024 + j];
          float rg = 1.f/(1.f + __expf(-gr));
          float zg = 1.f/(1.f + __expf(-gz));
          float ng = ftanh(gnn + rg*ghn);
          hn1 = (1.f - zg)*ng + zg*Hr[j];
        }
        st_devf(&f.h[(size_t)b*512 + tid], hn0);
        st_devf(&f.h[(size_t)b*512 + tid + 256], hn1);
        int sw = (b & 7) << 3;
        u16 hi0 = f2b(hn0);
        st_dev(&f.h2[(size_t)b*1024 + (tid ^ sw)], hi0);
        st_dev(&f.h2[(size_t)b*1024 + ((512 + tid) ^ sw)], f2b(hn0 - b2f(hi0)));
        u16 hi1 = f2b(hn1);
        st_dev(&f.h2[(size_t)b*1024 + ((tid + 256) ^ sw)], hi1);
        st_dev(&f.h2[(size_t)b*1024 + ((768 + tid) ^ sw)], f2b(hn1 - b2f(hi1)));

        float sm = hn0 + hn1;
        for (int o = 32; o; o >>= 1) sm += __shfl_down(sm, o);
        if (!lane) sred[wave] = sm;
        __syncthreads();
        if (!tid) sred[8] = (sred[0] + sred[1] + sred[2] + sred[3]) * (1.f/512.f);
        __syncthreads();
        float mu = sred[8];
        float d0 = hn0 - mu, d1 = hn1 - mu;
        float ss = d0*d0 + d1*d1;
        for (int o = 32; o; o >>= 1) ss += __shfl_down(ss, o);
        if (!lane) sred[wave + 4] = ss;
        __syncthreads();
        if (!tid) sred[9] = (sred[4] + sred[5] + sred[6] + sred[7]) * (1.f/512.f) + 1e-5f;
        __syncthreads();
        float isd = rsqrtf(sred[9]);
        size_t ob = ((size_t)b*Ssz + s)*512;
        f.out[ob + tid]       = d0*isd*gam0 + bet0;
        f.out[ob + tid + 256] = d1*isd*gam1 + bet1;
        __syncthreads();
      }
    }
    gbar();
  }
}

/* ---------------- launcher ---------------- */

extern "C" void kernel_launch(void* const* d_in, const int* in_sizes, int n_in,
                              void* d_out, int out_size, void* d_ws, size_t ws_size,
                              hipStream_t stream){
  (void)in_sizes; (void)n_in; (void)out_size; (void)ws_size;
  const float* tp    = (const float*)d_in[0];
  const float* vals  = (const float*)d_in[1];
  const float* w1    = (const float*)d_in[2];
  const float* b1v   = (const float*)d_in[3];
  const float* w2    = (const float*)d_in[4];
  const float* b2v   = (const float*)d_in[5];
  const float* wih   = (const float*)d_in[6];
  const float* whh   = (const float*)d_in[7];
  const float* bih   = (const float*)d_in[8];
  const float* bhh   = (const float*)d_in[9];
  const float* gamma = (const float*)d_in[10];
  const float* beta  = (const float*)d_in[11];
  float* out = (float*)d_out;

  uint8_t* w = (uint8_t*)d_ws;
  size_t off = 0;
  auto alloc = [&](size_t bytes)->void*{
    void* pp = w + off; off += (bytes + 255) & ~(size_t)255; return pp; };
  float* h      = (float*)alloc((size_t)Bsz*Hsz*4);
  u16*   h2     = (u16*)alloc((size_t)Bsz*NTWO*2);
  u16*   tbuf   = (u16*)alloc((size_t)2*Bsz*NTWO*2);   // double-buffered
  u16*   Ta     = (u16*)alloc((size_t)Bsz*NTWO*2);
  float* GH     = (float*)alloc((size_t)Bsz*1536*4);
  float* GI     = (float*)alloc((size_t)Bsz*1536*4);
  u16*   Gt     = (u16*)alloc((size_t)NTWO*NTWO*2);
  u16*   w1tl   = (u16*)alloc((size_t)NTWO*Hsz*2);
  u16*   w1ts   = (u16*)alloc((size_t)NTWO*Hsz*2);
  u16*   w2bf   = (u16*)alloc((size_t)NTWO*Hsz*2);
  u16*   w2ts   = (u16*)alloc((size_t)Hsz*NTWO*2);
  u16*   whhs   = (u16*)alloc((size_t)1536*Hsz*2);
  u16*   wixs   = (u16*)alloc((size_t)1536*128*2);
  u16*   xs     = (u16*)alloc((size_t)Ssz*Bsz*Fsz*2);
  float* wdt    = (float*)alloc(1536*4);
  float* uvec   = (float*)alloc(NTWO*4);
  float* tsm    = (float*)alloc(Ssz*4);
  float* subs   = (float*)alloc(Ssz*4);
  float* dti    = (float*)alloc((size_t)Bsz*Ssz*4);
  u32*   bar    = (u32*)alloc(1024);

  hipLaunchKernelGGL(zero_k, dim3(2048), dim3(256), 0, stream, h, h2, bar);
  hipLaunchKernelGGL(tsm_k,  dim3(128),  dim3(256), 0, stream, tp, tsm);
  hipLaunchKernelGGL(sub_k,  dim3(1),    dim3(128), 0, stream, tsm, subs);
  hipLaunchKernelGGL(dti_k,  dim3(256),  dim3(256), 0, stream, tp, dti);
  hipLaunchKernelGGL(tr1_k,  dim3(2048), dim3(256), 0, stream, w1, w1tl, w1ts);
  hipLaunchKernelGGL(cvt_k,  dim3(2048), dim3(256), 0, stream, w2, w2bf, NTWO*Hsz);
  hipLaunchKernelGGL(w2t_k,  dim3(2048), dim3(256), 0, stream, w2, w2ts);
  hipLaunchKernelGGL(whh_k,  dim3(3072), dim3(256), 0, stream, whh, whhs);
  hipLaunchKernelGGL(wixs_k, dim3(768),  dim3(256), 0, stream, wih, wixs);
  hipLaunchKernelGGL(wdt_k,  dim3(6),    dim3(256), 0, stream, wih, wdt);
  hipLaunchKernelGGL(xsl_k,  dim3(32768),dim3(256), 0, stream, vals, xs);
  hipLaunchKernelGGL(u_k,    dim3(4),    dim3(256), 0, stream, b2v, w1tl, uvec);
  {
    GArgs g{};
    g.A = w1tl; g.Bt = w2bf; g.a_rs = Hsz; g.b_rs = Hsz; g.K = Hsz;
    g.kmask = 511; g.GtOut = Gt;
    hipLaunchKernelGGL(gemm_k, dim3(16,32), dim3(256), 0, stream, g);
  }

  FArgs fa{};
  fa.Gt = Gt; fa.w1t = w1ts; fa.w2t = w2ts; fa.whh = whhs; fa.wix = wixs; fa.xs = xs;
  fa.t = tbuf; fa.Ta = Ta; fa.h2 = h2;
  fa.h = h; fa.GI = GI; fa.GH = GH; fa.out = out;
  fa.subs = subs; fa.dti = dti; fa.u = uvec; fa.b1 = b1v; fa.b2 = b2v;
  fa.bhh = bhh; fa.bih = bih; fa.wdt = wdt; fa.gamma = gamma; fa.beta = beta;
  fa.bar = bar;

  void* params[] = { (void*)&fa };
  hipError_t e = hipLaunchCooperativeKernel((const void*)fused_k, dim3(256), dim3(256),
                                            params, 0u, stream);
  if (e != hipSuccess){
    hipLaunchKernelGGL(fused_k, dim3(256), dim3(256), 0, stream, fa);
  }
}

// Round 3
// 31416.733 us; speedup vs baseline: 3.5007x; 1.5465x over previous
//
#include <hip/hip_runtime.h>
#include <cstdint>
#include <cstddef>

#define Bsz 512
#define Ssz 128
#define Fsz 128
#define Hsz 512
#define NTWO 1024  /* 2H */

typedef __attribute__((ext_vector_type(8))) short short8;
typedef __attribute__((ext_vector_type(4))) float f32x4;
typedef unsigned int u32;
typedef unsigned short u16;

__device__ __forceinline__ float b2f(u16 u){
  union { u32 i; float f; } v; v.i = ((u32)u) << 16; return v.f;
}
__device__ __forceinline__ u16 f2b(float f){
  union { float f; u32 i; } v; v.f = f;
  u32 x = v.i;
  return (u16)((x + 0x7fffu + ((x >> 16) & 1u)) >> 16);
}
// AUX: 0 = normal (read-only data, L2-cached). 16 = SC1 device-scope (coherent at L3).
template<int AUX>
__device__ __forceinline__ void g2l16(const void* g, void* l){
  __builtin_amdgcn_global_load_lds((const __attribute__((address_space(1))) u32*)g,
                                   (__attribute__((address_space(3))) u32*)l, 16, 0, AUX);
}
__device__ __forceinline__ void st_devf(float* p, float v){
  __hip_atomic_store(p, v, __ATOMIC_RELAXED, __HIP_MEMORY_SCOPE_AGENT);
}
// device-scope 16B store: write-through past L2 (cross-XCD visible at L3)
__device__ __forceinline__ void stg16_sc(void* p, short8 v){
  asm volatile("global_store_dwordx4 %0, %1, off sc0 sc1" :: "v"(p), "v"(v) : "memory");
}
// volatile 16B load (prevents hoisting out of the step loop)
__device__ __forceinline__ short8 ldg16(const void* p){
  short8 r;
  asm volatile("global_load_dwordx4 %0, %1, off" : "=v"(r) : "v"(p) : "memory");
  return r;
}
__device__ __forceinline__ float ftanh(float x){
  float a = fabsf(x);
  float e = __expf(-2.f*a);
  float t = __fdividef(1.f - e, 1.f + e);
  return copysignf(t, x);
}
__device__ __forceinline__ void vwait(int n){
  switch(n){
    case 0: asm volatile("s_waitcnt vmcnt(0)" ::: "memory"); break;
    case 1: asm volatile("s_waitcnt vmcnt(1)" ::: "memory"); break;
    case 2: asm volatile("s_waitcnt vmcnt(2)" ::: "memory"); break;
    case 4: asm volatile("s_waitcnt vmcnt(4)" ::: "memory"); break;
    default: break;
  }
}

// RK45 (Dormand-Prince) b-coefficients
#define RB1 0.09114583333333333f
#define RB3 0.4492362982929021f
#define RB4 0.6510416666666666f
#define RB5 (-0.3223921568627451f)
#define RB6 0.13095238095238096f
#define MFMA16 __builtin_amdgcn_mfma_f32_16x16x32_bf16

/* ---------------- setup kernels ---------------- */

__global__ void zero_k(float* h, u16* h2, u32* bar){
  int i = blockIdx.x*256 + threadIdx.x;           // grid 2048*256 = 524288
  if (i < Bsz*Hsz) h[i] = 0.f;
  h2[i] = 0;
  if (i < 512) bar[i] = 0u;
}

__global__ void tsm_k(const float* tp, float* tsm){
  int s = blockIdx.x, tid = threadIdx.x;
  __shared__ float red[8];
  float v = tp[(size_t)tid*Ssz + s] + tp[(size_t)(tid + 256)*Ssz + s];
  int wave = tid >> 6, lane = tid & 63;
  for (int o = 32; o; o >>= 1) v += __shfl_down(v, o);
  if (!lane) red[wave] = v;
  __syncthreads();
  if (!tid) tsm[s] = (red[0] + red[1] + red[2] + red[3]) * (1.f/(512.f*72.f));
}

__global__ void sub_k(const float* tsm, float* subs){
  int i = threadIdx.x;
  if (i < Ssz){
    float dtm = (i == 0) ? 0.f : (tsm[i] - tsm[i-1]);
    float de = (dtm > 1e-4f) ? dtm : 0.f;
    subs[i] = de * 0.125f;
  }
}

__global__ void dti_k(const float* tp, float* dti){
  int i = blockIdx.x*256 + threadIdx.x;
  int ss = i & 127;
  dti[i] = ss ? (tp[i] - tp[i-1]) : 0.f;
}

// w1 (512 x 1024) -> lin[n][k] = w1[k][n] ; swz = same with k units XORed by (n&7)
__global__ void tr1_k(const float* w1, u16* lin, u16* swz){
  int i = blockIdx.x*256 + threadIdx.x;           // 524288
  int n = i >> 9, k = i & 511;
  u16 v = f2b(w1[(size_t)k*NTWO + n]);
  lin[i] = v;
  swz[(size_t)n*512 + (k ^ ((n&7)<<3))] = v;
}

__global__ void cvt_k(const float* src, u16* dst, int n){
  int i = blockIdx.x*256 + threadIdx.x;
  if (i < n) dst[i] = f2b(src[i]);
}

// w2 (1024 x 512) -> w2t[n][k] = w2[k][n] swizzled (n<512, k<1024)
__global__ void w2t_k(const float* w2, u16* dst){
  int i = blockIdx.x*256 + threadIdx.x;           // 524288
  int n = i >> 10, k = i & 1023;
  dst[(size_t)n*1024 + (k ^ ((n&7)<<3))] = f2b(w2[(size_t)k*Hsz + n]);
}

// whh (1536 x 512) -> swizzled
__global__ void whh_k(const float* whh, u16* dst){
  int i = blockIdx.x*256 + threadIdx.x;           // 786432
  int n = i >> 9, k = i & 511;
  dst[(size_t)n*512 + (k ^ ((n&7)<<3))] = f2b(whh[i]);
}

// wih (1536 x 129) -> wix[n][k] swizzled, k<128
__global__ void wixs_k(const float* wih, u16* dst){
  int i = blockIdx.x*256 + threadIdx.x;           // 196608
  int n = i >> 7, k = i & 127;
  dst[(size_t)n*128 + (k ^ ((n&7)<<3))] = f2b(wih[(size_t)n*129 + k]);
}

__global__ void wdt_k(const float* wih, float* wdt){
  int i = blockIdx.x*256 + threadIdx.x;
  if (i < 1536) wdt[i] = wih[(size_t)i*129 + 128];
}

// vals (B,S,F) f32 -> xs[s][b][f] bf16 swizzled on f by (b&7)
__global__ void xsl_k(const float* vals, u16* dst){
  int i = blockIdx.x*256 + threadIdx.x;           // 8388608
  int p = i & 127;
  int b = (i >> 7) & 511;
  int s = i >> 16;
  int f = p ^ ((b&7)<<3);
  dst[i] = f2b(vals[((size_t)b*Ssz + s)*Fsz + f]);
}

__global__ void u_k(const float* b2v, const u16* w1t, float* u){
  int i = blockIdx.x*256 + threadIdx.x;
  if (i < NTWO){
    float acc = 0.f;
    for (int j = 0; j < Hsz; ++j) acc += b2v[j] * b2f(w1t[(size_t)i*Hsz + j]);
    u[i] = acc;
  }
}

/* --------- Gt = (w2@w1)^T setup GEMM (plain [n][k] output) --------- */
struct GArgs {
  const u16* A; const u16* Bt;
  int a_rs, b_rs, K, kmask;
  u16* GtOut;
};

__launch_bounds__(256)
__global__ void gemm_k(GArgs g){
  __shared__ __align__(16) u16 lA[2][64*64];
  __shared__ __align__(16) u16 lB[2][32*64];
  const int tid = threadIdx.x;
  const int wave = tid >> 6, lane = tid & 63;
  const int quad = lane >> 4, l16 = lane & 15;
  const int mb = blockIdx.x * 64;
  const int nb = blockIdx.y * 32;
  f32x4 acc0 = {0.f,0.f,0.f,0.f}, acc1 = {0.f,0.f,0.f,0.f};

  const int r0 = tid >> 3,         c0 = (tid & 7) ^ (r0 & 7);
  const int r1 = (256 + tid) >> 3, c1 = (tid & 7) ^ (r1 & 7);

  const int am = wave*16 + l16;
  const int aoff0 = am*64 + (((quad    ) ^ (am & 7)) << 3);
  const int aoff1 = am*64 + (((4 + quad) ^ (am & 7)) << 3);
  const int bn0 = l16, bn1 = 16 + l16;
  const int boff00 = bn0*64 + (((quad    ) ^ (bn0 & 7)) << 3);
  const int boff01 = bn0*64 + (((4 + quad) ^ (bn0 & 7)) << 3);
  const int boff10 = bn1*64 + (((quad    ) ^ (bn1 & 7)) << 3);
  const int boff11 = bn1*64 + (((4 + quad) ^ (bn1 & 7)) << 3);

  const int nkb = g.K >> 6;
  {
    g2l16<0>(g.A  + (size_t)(mb + r0) * g.a_rs + ((c0 << 3)),             &lA[0][tid << 3]);
    g2l16<0>(g.A  + (size_t)(mb + r1) * g.a_rs + ((c1 << 3)),             &lA[0][(256 + tid) << 3]);
    g2l16<0>(g.Bt + (size_t)(nb + r0) * g.b_rs + (((c0 << 3)) & g.kmask), &lB[0][tid << 3]);
  }
  __syncthreads();
  for (int kb = 0; kb < nkb; ++kb){
    int buf = kb & 1;
    if (kb + 1 < nkb){
      int k0 = (kb + 1) << 6, nbuf = buf ^ 1;
      g2l16<0>(g.A  + (size_t)(mb + r0) * g.a_rs + (k0 + (c0 << 3)),             &lA[nbuf][tid << 3]);
      g2l16<0>(g.A  + (size_t)(mb + r1) * g.a_rs + (k0 + (c1 << 3)),             &lA[nbuf][(256 + tid) << 3]);
      g2l16<0>(g.Bt + (size_t)(nb + r0) * g.b_rs + ((k0 + (c0 << 3)) & g.kmask), &lB[nbuf][tid << 3]);
    }
    short8 a0  = *(const short8*)&lA[buf][aoff0];
    short8 a1  = *(const short8*)&lA[buf][aoff1];
    short8 b00 = *(const short8*)&lB[buf][boff00];
    short8 b01 = *(const short8*)&lB[buf][boff01];
    short8 b10 = *(const short8*)&lB[buf][boff10];
    short8 b11 = *(const short8*)&lB[buf][boff11];
    acc0 = MFMA16(a0, b00, acc0, 0, 0, 0);
    acc0 = MFMA16(a1, b01, acc0, 0, 0, 0);
    acc1 = MFMA16(a0, b10, acc1, 0, 0, 0);
    acc1 = MFMA16(a1, b11, acc1, 0, 0, 0);
    __syncthreads();
  }
  #pragma unroll
  for (int cb = 0; cb < 2; ++cb){
    f32x4 a = cb ? acc1 : acc0;
    int n = nb + cb*16 + l16;
    #pragma unroll
    for (int r = 0; r < 4; ++r){
      int m = mb + wave*16 + quad*4 + r;
      g.GtOut[(size_t)m*NTWO + n] = f2b(a[r]);    // plain layout [out_col][k]
    }
  }
}

/* ---------------- fused persistent kernel ---------------- */

struct FArgs {
  const u16 *Gt, *w1t, *w2t, *whh, *wix, *xs;
  u16 *t, *Ta, *h2;           // t double-buffered: t + buf*Bsz*NTWO
  float *h, *GI, *GH, *out;
  const float *subs, *dti, *u, *b1, *b2, *bhh, *bih, *wdt, *gamma, *beta;
  u32 *bar;                   // 32 groups x 16 u32 (8 used)
};

__launch_bounds__(512, 2)
__global__ void fused_k(FArgs f){
  __shared__ __align__(16) u16 sAfull[16*1024];    // 32 KB A slab (16 rows x 1024)
  __shared__ __align__(16) u16 sBring[3][8192];    // 48 KB B ring / GI-B / h-stage
  __shared__ __align__(16) u16 sTpack[2][2048];    // 8 KB pack tiles
  __shared__ float sRed[1024];                     // 4 KB K-split reduce
  __shared__ float sLN[16];

  const int tid = threadIdx.x;
  const int wave = tid >> 6, lane = tid & 63;
  const int quad = (lane >> 4) & 3, l16 = lane & 15;
  const int l7 = l16 & 7;
  const int bid = blockIdx.x;
  const int g   = bid & 31;       // 32 groups (co-XCD-ish under bid%8 heuristic)
  const int jb  = bid >> 5;       // 0..7 within group
  const int r0  = g * 16;         // group rows [r0, r0+16)
  const int cb0 = jb * 128;       // ODE/p col slice
  const int wcol = wave*16 + l16; // col within 128-slice (ODE/p/GH-p1/GI-p1)
  const int cw4 = (wave & 3)*16 + l16; // col within 64-slice (finish/GH-p2)

  u32* flagp = f.bar + g*16;
  u32 epA = 1, epW = 0;
  u16* sBflat = &sBring[0][0];

  // per-thread constants
  const int   pcol = cb0 + wcol;
  const float uuv = f.u[pcol], bb1v = f.b1[pcol];
  const int   fcol = jb*64 + cw4;
  const float b2v = f.b2[fcol];
  const int   gcol1 = jb*192 + wcol;
  const int   gcol2 = jb*192 + 128 + cw4;
  const float bhh1 = f.bhh[gcol1], bih1 = f.bih[gcol1], wdt1 = f.wdt[gcol1];
  const float bhh2 = f.bhh[gcol2], bih2 = f.bih[gcol2], wdt2 = f.wdt[gcol2];
  const int   b0row = r0 + jb*2;  // GRU rows
  const int   j0 = tid & 255, grow = tid >> 8;
  const float gmA = f.gamma[j0], gmB = f.gamma[j0+256];
  const float btA = f.beta[j0],  btB = f.beta[j0+256];
  const size_t TSZ = (size_t)Bsz*NTWO;

  // initial arrive (epoch 1)
  if (tid == 0)
    __hip_atomic_store(&flagp[jb], 1u, __ATOMIC_RELAXED, __HIP_MEMORY_SCOPE_AGENT);

  auto arrive = [&](){
    ++epA;
    if (tid == 0)
      __hip_atomic_store(&flagp[jb], epA, __ATOMIC_RELAXED, __HIP_MEMORY_SCOPE_AGENT);
  };
  auto waitall = [&](){
    ++epW;
    if (wave == 0){
      for (;;){
        u32 fv = (lane < 8)
          ? __hip_atomic_load(&flagp[lane], __ATOMIC_RELAXED, __HIP_MEMORY_SCOPE_AGENT)
          : 0xFFFFFFFFu;
        if (__all(fv >= epW)) break;
        __builtin_amdgcn_s_sleep(1);
      }
    }
    __syncthreads();
  };

  // stage 16 rows x 1024 of a 1024-wide swizzled-global array (linear copy)
  auto stageA16 = [&](const u16* gsrc){
    #pragma unroll
    for (int i = 0; i < 4; ++i){
      int u = tid + i*512; int row = u >> 7; int k8 = u & 127;
      g2l16<16>(gsrc + (((size_t)(r0+row)) << 10) + (k8 << 3), &sAfull[u << 3]);
    }
  };
  // B ring stage: 128 cols x 64k (2 units/thread)
  auto stageB2 = [&](const u16* gB, int burow, int bc, int slot){
    #pragma unroll
    for (int i = 0; i < 2; ++i){
      int u = tid + i*512; int col = u >> 3; int k8 = u & 7;
      g2l16<0>(gB + (size_t)col*(burow<<3) + (bc<<6) + (k8<<3), &sBring[slot][u << 3]);
    }
  };
  // B ring stage: 64 cols x 64k (1 unit/thread)
  auto stageB1 = [&](const u16* gB, int burow, int bc, int slot){
    int col = tid >> 3; int k8 = tid & 7;
    g2l16<0>(gB + (size_t)col*(burow<<3) + (bc<<6) + (k8<<3), &sBring[slot][tid << 3]);
  };
  auto afrag = [&](int c, int kk)->short8 {
    return *(const short8*)&sAfull[(l16<<10) + (((c*8 + kk*4 + quad) ^ l7)<<3)];
  };
  auto bfragW = [&](int slot, int kk)->short8 {  // wave's 16-col slice of 128-col chunk
    return *(const short8*)&sBring[slot][(wcol<<6) + ((((kk<<2)+quad) ^ (wcol&7))<<3)];
  };
  auto bfrag4 = [&](int slot, int kk)->short8 {  // 64-col chunk
    return *(const short8*)&sBring[slot][(cw4<<6) + ((((kk<<2)+quad) ^ (cw4&7))<<3)];
  };

  f32x4 p_, T_, q0, q1, q2, q3, q4;
  short8 bfr[32];

  for (int s = 0; s < Ssz; ++s){
    const float sub = f.subs[s];
    const bool act = (sub > 0.f);   // uniform within group

    waitall();  // h2/h ready from previous step's GRU (or initial)

    if (act){
      { // ---- p = h2@w1 + b1 ; t0 = tanh(p) ; T = sub*RB1*t ----
        stageA16(f.h2);
        const u16* wb = f.w1t + ((size_t)cb0)*512;
        stageB2(wb, 64, 0, 0); stageB2(wb, 64, 1, 1);
        f32x4 acc = {0.f,0.f,0.f,0.f};
        for (int c = 0; c < 16; ++c){
          vwait((c+1 < 16) ? 2 : 0);
          __builtin_amdgcn_s_barrier();
          if (c+2 < 16) stageB2(wb, 64, (c+2)&7, (c+2)%3);
          short8 a0 = afrag(c,0), a1 = afrag(c,1);
          short8 b0 = bfragW(c%3,0), b1 = bfragW(c%3,1);
          acc = MFMA16(a0, b0, acc, 0,0,0);
          acc = MFMA16(a1, b1, acc, 0,0,0);
        }
        __syncthreads();
        #pragma unroll
        for (int r = 0; r < 4; ++r){
          float v = acc[r] + bb1v; p_[r] = v;
          float tv = ftanh(v);     T_[r] = sub*RB1*tv;
          sTpack[0][(quad*4+r)*128 + wcol] = f2b(tv);
        }
        __syncthreads();
        if (tid < 256){
          int row = tid >> 4, c8 = tid & 15;
          short8 v = *(const short8*)&sTpack[0][tid << 3];
          stg16_sc(f.t + (((size_t)(r0+row))<<10) + ((size_t)((jb<<4) + (c8 ^ (row&7)))<<3), v);
        }
        vwait(0); __syncthreads();
        arrive();
      }

      // ---- load resident B-frags (Gt cols for this wave) from L2 ----
      {
        const u16* gtb = f.Gt + ((size_t)pcol << 10) + (quad << 3);
        #pragma unroll
        for (int cc = 0; cc < 32; ++cc) bfr[cc] = ldg16(gtb + cc*32);
        vwait(0);
      }

      // ---- 47 RK45 stage GEMMs ----
      int par = 0;
      for (int ssb = 0; ssb < 8; ++ssb){
        for (int st = 1; st <= 6; ++st){
          if (ssb == 7 && st == 6) break;
          const int wt = (ssb == 7 && st == 5) ? 1 : 0;
          waitall();
          stageA16(f.t + (size_t)par*TSZ);
          vwait(0); __syncthreads();
          f32x4 aA = {0.f,0.f,0.f,0.f}, aB = {0.f,0.f,0.f,0.f};
          #pragma unroll
          for (int cc = 0; cc < 32; cc += 2){
            short8 x0 = *(const short8*)&sAfull[(l16<<10) + ((((cc<<2)+quad) ^ l7)<<3)];
            short8 x1 = *(const short8*)&sAfull[(l16<<10) + (((((cc+1)<<2)+quad) ^ l7)<<3)];
            aA = MFMA16(x0, bfr[cc],   aA, 0,0,0);
            aB = MFMA16(x1, bfr[cc+1], aB, 0,0,0);
          }
          f32x4 acc; 
          #pragma unroll
          for (int r = 0; r < 4; ++r) acc[r] = aA[r] + aB[r];
          #pragma unroll
          for (int r = 0; r < 4; ++r){
            float qv = acc[r] + uuv;
            float zs;
            if (st == 1){ q0[r] = qv; zs = 0.2f*qv; }
            else if (st == 2){ q1[r] = qv; zs = 0.075f*q0[r] + 0.225f*qv; }
            else if (st == 3){ q2[r] = qv;
              zs = (44.f/45.f)*q0[r] + (-56.f/15.f)*q1[r] + (32.f/9.f)*qv; }
            else if (st == 4){ q3[r] = qv;
              zs = 2.9525986892242035f*q0[r] + (-11.595793324188385f)*q1[r]
                 + 9.822892851699436f*q2[r] + (-0.2908093278463649f)*qv; }
            else if (st == 5){ q4[r] = qv;
              zs = 2.8462752525252526f*q0[r] + (-10.757575757575758f)*q1[r]
                 + 8.906422717743473f*q2[r] + 0.2784090909090909f*q3[r]
                 + (-0.2735313036020583f)*qv; }
            else {
              zs = RB1*q0[r] + RB3*q2[r] + RB4*q3[r] + RB5*q4[r] + RB6*qv;
            }
            float tv;
            if (st < 6){
              float z = p_[r] + sub*zs;
              tv = ftanh(z);
              if (st >= 2){
                float bn = (st == 2) ? RB3 : (st == 3) ? RB4 : (st == 4) ? RB5 : RB6;
                T_[r] += sub*bn*tv;
              }
            } else {
              p_[r] += sub*zs;
              tv = ftanh(p_[r]);
              T_[r] += sub*RB1*tv;
            }
            sTpack[0][(quad*4+r)*128 + wcol] = f2b(wt ? T_[r] : tv);
          }
          __syncthreads();
          if (tid < 256){
            int row = tid >> 4, c8 = tid & 15;
            short8 v = *(const short8*)&sTpack[0][tid << 3];
            u16* dst = wt ? f.Ta : (f.t + (size_t)(par^1)*TSZ);
            stg16_sc(dst + (((size_t)(r0+row))<<10) + ((size_t)((jb<<4) + (c8 ^ (row&7)))<<3), v);
          }
          vwait(0); __syncthreads();
          arrive();
          par ^= 1;
        }
      }

      { // ---- h += Ta@w2 + dt_eff*b2 ; h2 hi/lo ----
        waitall();
        stageA16(f.Ta);
        const u16* wb = f.w2t + ((size_t)(jb*64)) * 1024;
        stageB1(wb, 128, 0, 0); stageB1(wb, 128, 1, 1);
        f32x4 fa = {0.f,0.f,0.f,0.f};
        for (int c = 0; c < 16; ++c){
          vwait((c+1 < 16) ? 1 : 0);
          __builtin_amdgcn_s_barrier();
          if (c+2 < 16) stageB1(wb, 128, c+2, (c+2)%3);
          if ((c >> 3) == (wave >> 2)){
            short8 a0 = afrag(c,0), a1 = afrag(c,1);
            short8 b0 = bfrag4(c%3,0), b1 = bfrag4(c%3,1);
            fa = MFMA16(a0, b0, fa, 0,0,0);
            fa = MFMA16(a1, b1, fa, 0,0,0);
          }
        }
        __syncthreads();
        if (tid < 256){
          int row = tid >> 4, c4 = tid & 15;
          g2l16<16>(f.h + (size_t)(r0+row)*512 + jb*64 + (c4<<2), &sBflat[tid << 3]);
        }
        if (wave >= 4){
          #pragma unroll
          for (int r = 0; r < 4; ++r)
            sRed[(wave&3)*256 + (quad*4+r)*16 + l16] = fa[r];
        }
        __syncthreads();
        if (wave < 4){
          vwait(0);
          const float* HS = (const float*)sBflat;
          #pragma unroll
          for (int r = 0; r < 4; ++r){
            int lrow = quad*4 + r;
            float hv = HS[lrow*64 + cw4] + fa[r] + sRed[(wave&3)*256 + lrow*16 + l16]
                     + 8.f*sub*b2v;
            st_devf(&f.h[(size_t)(r0+lrow)*512 + fcol], hv);
            u16 hi = f2b(hv);
            sTpack[0][lrow*64 + cw4] = hi;
            sTpack[0][1024 + lrow*64 + cw4] = f2b(hv - b2f(hi));
          }
        }
        __syncthreads();
        if (tid < 256){
          int half = tid >> 7, row = (tid >> 3) & 15, c8 = tid & 7;
          short8 v = *(const short8*)&sTpack[0][tid << 3];
          size_t gu = (((size_t)(r0+row)) << 7) + (half<<6) + (jb<<3) + (c8 ^ (row&7));
          stg16_sc(f.h2 + (gu << 3), v);
        }
        vwait(0); __syncthreads();
        arrive();
        waitall();   // h2 fully updated by all 8 blocks
      }
    }

    { // ---- GH = h2@whh^T + bhh (pass1: 128 cols, pass2: 64 cols K-split) ----
      stageA16(f.h2);
      const u16* wb1 = f.whh + ((size_t)(jb*192)) * 512;
      stageB2(wb1, 64, 0, 0); stageB2(wb1, 64, 1, 1);
      f32x4 gh = {0.f,0.f,0.f,0.f};
      for (int c = 0; c < 16; ++c){
        vwait((c+1 < 16) ? 2 : 0);
        __builtin_amdgcn_s_barrier();
        if (c+2 < 16) stageB2(wb1, 64, (c+2)&7, (c+2)%3);
        short8 a0 = afrag(c,0), a1 = afrag(c,1);
        short8 b0 = bfragW(c%3,0), b1 = bfragW(c%3,1);
        gh = MFMA16(a0, b0, gh, 0,0,0);
        gh = MFMA16(a1, b1, gh, 0,0,0);
      }
      #pragma unroll
      for (int r = 0; r < 4; ++r)
        st_devf(&f.GH[(size_t)(r0+quad*4+r)*1536 + gcol1], gh[r] + bhh1);
      __syncthreads();
      // pass 2
      const u16* wb2 = f.whh + ((size_t)(jb*192+128)) * 512;
      stageB1(wb2, 64, 0, 0); stageB1(wb2, 64, 1, 1);
      f32x4 g2 = {0.f,0.f,0.f,0.f};
      for (int c = 0; c < 8; ++c){
        vwait((c+1 < 8) ? 1 : 0);
        __builtin_amdgcn_s_barrier();
        if (c+2 < 8) stageB1(wb2, 64, c+2, (c+2)%3);
        int ac = c + ((wave >= 4) ? 8 : 0);
        short8 a0 = afrag(ac,0), a1 = afrag(ac,1);
        short8 b0 = bfrag4(c%3,0), b1 = bfrag4(c%3,1);
        g2 = MFMA16(a0, b0, g2, 0,0,0);
        g2 = MFMA16(a1, b1, g2, 0,0,0);
      }
      __syncthreads();
      if (wave >= 4){
        #pragma unroll
        for (int r = 0; r < 4; ++r)
          sRed[(wave&3)*256 + (quad*4+r)*16 + l16] = g2[r];
      }
      __syncthreads();
      if (wave < 4){
        #pragma unroll
        for (int r = 0; r < 4; ++r){
          float v = g2[r] + sRed[wave*256 + (quad*4+r)*16 + l16];
          st_devf(&f.GH[(size_t)(r0+quad*4+r)*1536 + gcol2], v + bhh2);
        }
      }
      __syncthreads();
    }

    { // ---- GI = xs@wix^T + dti*wdt + bih ----
      if (tid < 256){
        int row = tid >> 4, k16 = tid & 15;
        g2l16<0>(f.xs + (((size_t)s*512 + r0 + row) << 7) + (k16 << 3), &sAfull[tid << 3]);
      }
      #pragma unroll
      for (int i = 0; i < 6; ++i){
        int u = tid + i*512; int col = u >> 4; int k16 = u & 15;
        g2l16<0>(f.wix + (((size_t)(jb*192 + col)) << 7) + (k16 << 3), &sBflat[u << 3]);
      }
      vwait(0); __syncthreads();
      f32x4 gi = {0.f,0.f,0.f,0.f};
      #pragma unroll
      for (int c = 0; c < 4; ++c){
        short8 a = *(const short8*)&sAfull[(l16<<7) + ((((c<<2)+quad) ^ l7)<<3)];
        short8 b = *(const short8*)&sBflat[(wcol<<7) + ((((c<<2)+quad) ^ (wcol&7))<<3)];
        gi = MFMA16(a, b, gi, 0,0,0);
      }
      #pragma unroll
      for (int r = 0; r < 4; ++r){
        float dv = f.dti[((size_t)(r0+quad*4+r) << 7) + s];
        st_devf(&f.GI[(size_t)(r0+quad*4+r)*1536 + gcol1], gi[r] + bih1 + dv*wdt1);
      }
      if (wave < 4){
        int cw2 = 128 + cw4;
        f32x4 gi2 = {0.f,0.f,0.f,0.f};
        #pragma unroll
        for (int c = 0; c < 4; ++c){
          short8 a = *(const short8*)&sAfull[(l16<<7) + ((((c<<2)+quad) ^ l7)<<3)];
          short8 b = *(const short8*)&sBflat[(cw2<<7) + ((((c<<2)+quad) ^ (cw2&7))<<3)];
          gi2 = MFMA16(a, b, gi2, 0,0,0);
        }
        #pragma unroll
        for (int r = 0; r < 4; ++r){
          float dv = f.dti[((size_t)(r0+quad*4+r) << 7) + s];
          st_devf(&f.GI[(size_t)(r0+quad*4+r)*1536 + gcol2], gi2[r] + bih2 + dv*wdt2);
        }
      }
      vwait(0); __syncthreads();
      arrive();
    }

    { // ---- GRU + LayerNorm (2 rows per block) ----
      waitall();
      #pragma unroll
      for (int i = 0; i < 4; ++i){
        int u = tid + i*512;
        if (u < 1792){
          const float* src;
          if (u < 768){ int row = (u >= 384); int off = u - row*384;
            src = f.GI + (size_t)(b0row+row)*1536 + (off<<2); }
          else if (u < 1536){ int v2 = u - 768; int row = (v2 >= 384); int off = v2 - row*384;
            src = f.GH + (size_t)(b0row+row)*1536 + (off<<2); }
          else { int v2 = u - 1536; int row = v2 >> 7; int off = v2 & 127;
            src = f.h + (size_t)(b0row+row)*512 + (off<<2); }
          g2l16<16>(src, &sAfull[u << 3]);
        }
      }
      vwait(0); __syncthreads();
      const float* LSf = (const float*)sAfull;
      const float* GIr = LSf + grow*1536;
      const float* GHr = LSf + 3072 + grow*1536;
      const float* Hr  = LSf + 6144 + grow*512;
      float hn0, hn1;
      {
        float gr = GIr[j0] + GHr[j0];
        float gz = GIr[512 + j0] + GHr[512 + j0];
        float ng = ftanh(GIr[1024 + j0] + (1.f/(1.f + __expf(-gr)))*GHr[1024 + j0]);
        float zg = 1.f/(1.f + __expf(-gz));
        hn0 = (1.f - zg)*ng + zg*Hr[j0];
      }
      {
        int j = j0 + 256;
        float gr = GIr[j] + GHr[j];
        float gz = GIr[512 + j] + GHr[512 + j];
        float ng = ftanh(GIr[1024 + j] + (1.f/(1.f + __expf(-gr)))*GHr[1024 + j]);
        float zg = 1.f/(1.f + __expf(-gz));
        hn1 = (1.f - zg)*ng + zg*Hr[j];
      }
      st_devf(&f.h[(size_t)(b0row+grow)*512 + j0], hn0);
      st_devf(&f.h[(size_t)(b0row+grow)*512 + j0 + 256], hn1);
      u16* sT = &sTpack[0][0];
      u16 hi0 = f2b(hn0);
      sT[grow*1024 + j0]       = hi0;
      sT[grow*1024 + 512 + j0] = f2b(hn0 - b2f(hi0));
      u16 hi1 = f2b(hn1);
      sT[grow*1024 + 256 + j0] = hi1;
      sT[grow*1024 + 768 + j0] = f2b(hn1 - b2f(hi1));
      float sm = hn0 + hn1;
      for (int o = 32; o; o >>= 1) sm += __shfl_down(sm, o);
      if (!lane) sLN[wave] = sm;
      __syncthreads();
      if (tid == 0 || tid == 256){
        int rr = tid >> 8;
        sLN[8+rr] = (sLN[rr*4]+sLN[rr*4+1]+sLN[rr*4+2]+sLN[rr*4+3]) * (1.f/512.f);
      }
      __syncthreads();
      float mu = sLN[8+grow];
      float d0 = hn0 - mu, d1 = hn1 - mu;
      float ss = d0*d0 + d1*d1;
      for (int o = 32; o; o >>= 1) ss += __shfl_down(ss, o);
      if (!lane) sLN[wave] = ss;
      __syncthreads();
      if (tid == 0 || tid == 256){
        int rr = tid >> 8;
        sLN[12+rr] = rsqrtf((sLN[rr*4]+sLN[rr*4+1]+sLN[rr*4+2]+sLN[rr*4+3]) * (1.f/512.f) + 1e-5f);
      }
      __syncthreads();
      float isd = sLN[12+grow];
      size_t ob = ((size_t)(b0row+grow)*128 + s)*512;
      f.out[ob + j0]       = d0*isd*gmA + btA;
      f.out[ob + j0 + 256] = d1*isd*gmB + btB;
      __syncthreads();
      if (tid < 256){
        int row = tid >> 7, u8 = tid & 127;
        int b = b0row + row;
        short8 v = *(const short8*)&sT[(row*128 + u8) << 3];
        stg16_sc(f.h2 + (((size_t)b) << 10) + ((size_t)(u8 ^ (b&7)) << 3), v);
      }
      vwait(0); __syncthreads();
      arrive();
    }
  }
}

/* ---------------- launcher ---------------- */

extern "C" void kernel_launch(void* const* d_in, const int* in_sizes, int n_in,
                              void* d_out, int out_size, void* d_ws, size_t ws_size,
                              hipStream_t stream){
  (void)in_sizes; (void)n_in; (void)out_size; (void)ws_size;
  const float* tp    = (const float*)d_in[0];
  const float* vals  = (const float*)d_in[1];
  const float* w1    = (const float*)d_in[2];
  const float* b1v   = (const float*)d_in[3];
  const float* w2    = (const float*)d_in[4];
  const float* b2v   = (const float*)d_in[5];
  const float* wih   = (const float*)d_in[6];
  const float* whh   = (const float*)d_in[7];
  const float* bih   = (const float*)d_in[8];
  const float* bhh   = (const float*)d_in[9];
  const float* gamma = (const float*)d_in[10];
  const float* beta  = (const float*)d_in[11];
  float* out = (float*)d_out;

  uint8_t* w = (uint8_t*)d_ws;
  size_t off = 0;
  auto alloc = [&](size_t bytes)->void*{
    void* pp = w + off; off += (bytes + 255) & ~(size_t)255; return pp; };
  float* h      = (float*)alloc((size_t)Bsz*Hsz*4);
  u16*   h2     = (u16*)alloc((size_t)Bsz*NTWO*2);
  u16*   tbuf   = (u16*)alloc((size_t)2*Bsz*NTWO*2);   // double-buffered
  u16*   Ta     = (u16*)alloc((size_t)Bsz*NTWO*2);
  float* GH     = (float*)alloc((size_t)Bsz*1536*4);
  float* GI     = (float*)alloc((size_t)Bsz*1536*4);
  u16*   Gt     = (u16*)alloc((size_t)NTWO*NTWO*2);
  u16*   w1tl   = (u16*)alloc((size_t)NTWO*Hsz*2);
  u16*   w1ts   = (u16*)alloc((size_t)NTWO*Hsz*2);
  u16*   w2bf   = (u16*)alloc((size_t)NTWO*Hsz*2);
  u16*   w2ts   = (u16*)alloc((size_t)Hsz*NTWO*2);
  u16*   whhs   = (u16*)alloc((size_t)1536*Hsz*2);
  u16*   wixs   = (u16*)alloc((size_t)1536*128*2);
  u16*   xs     = (u16*)alloc((size_t)Ssz*Bsz*Fsz*2);
  float* wdt    = (float*)alloc(1536*4);
  float* uvec   = (float*)alloc(NTWO*4);
  float* tsm    = (float*)alloc(Ssz*4);
  float* subs   = (float*)alloc(Ssz*4);
  float* dti    = (float*)alloc((size_t)Bsz*Ssz*4);
  u32*   bar    = (u32*)alloc(2048);

  hipLaunchKernelGGL(zero_k, dim3(2048), dim3(256), 0, stream, h, h2, bar);
  hipLaunchKernelGGL(tsm_k,  dim3(128),  dim3(256), 0, stream, tp, tsm);
  hipLaunchKernelGGL(sub_k,  dim3(1),    dim3(128), 0, stream, tsm, subs);
  hipLaunchKernelGGL(dti_k,  dim3(256),  dim3(256), 0, stream, tp, dti);
  hipLaunchKernelGGL(tr1_k,  dim3(2048), dim3(256), 0, stream, w1, w1tl, w1ts);
  hipLaunchKernelGGL(cvt_k,  dim3(2048), dim3(256), 0, stream, w2, w2bf, NTWO*Hsz);
  hipLaunchKernelGGL(w2t_k,  dim3(2048), dim3(256), 0, stream, w2, w2ts);
  hipLaunchKernelGGL(whh_k,  dim3(3072), dim3(256), 0, stream, whh, whhs);
  hipLaunchKernelGGL(wixs_k, dim3(768),  dim3(256), 0, stream, wih, wixs);
  hipLaunchKernelGGL(wdt_k,  dim3(6),    dim3(256), 0, stream, wih, wdt);
  hipLaunchKernelGGL(xsl_k,  dim3(32768),dim3(256), 0, stream, vals, xs);
  hipLaunchKernelGGL(u_k,    dim3(4),    dim3(256), 0, stream, b2v, w1tl, uvec);
  {
    GArgs g{};
    g.A = w1tl; g.Bt = w2bf; g.a_rs = Hsz; g.b_rs = Hsz; g.K = Hsz;
    g.kmask = 511; g.GtOut = Gt;
    hipLaunchKernelGGL(gemm_k, dim3(16,32), dim3(256), 0, stream, g);
  }

  FArgs fa{};
  fa.Gt = Gt; fa.w1t = w1ts; fa.w2t = w2ts; fa.whh = whhs; fa.wix = wixs; fa.xs = xs;
  fa.t = tbuf; fa.Ta = Ta; fa.h2 = h2;
  fa.h = h; fa.GI = GI; fa.GH = GH; fa.out = out;
  fa.subs = subs; fa.dti = dti; fa.u = uvec; fa.b1 = b1v; fa.b2 = b2v;
  fa.bhh = bhh; fa.bih = bih; fa.wdt = wdt; fa.gamma = gamma; fa.beta = beta;
  fa.bar = bar;

  void* params[] = { (void*)&fa };
  hipError_t e = hipLaunchCooperativeKernel((const void*)fused_k, dim3(256), dim3(512),
                                            params, 0u, stream);
  if (e != hipSuccess){
    hipLaunchKernelGGL(fused_k, dim3(256), dim3(512), 0, stream, fa);
  }
}

// Round 5
// 30250.122 us; speedup vs baseline: 3.6357x; 1.0386x over previous
//
#include <hip/hip_runtime.h>
#include <cstdint>
#include <cstddef>

#define Bsz 512
#define Ssz 128
#define Fsz 128
#define Hsz 512
#define NTWO 1024  /* 2H */

typedef __attribute__((ext_vector_type(8))) short short8;
typedef __attribute__((ext_vector_type(4))) float f32x4;
typedef unsigned int u32;
typedef unsigned short u16;

__device__ __forceinline__ float b2f(u16 u){
  union { u32 i; float f; } v; v.i = ((u32)u) << 16; return v.f;
}
__device__ __forceinline__ u16 f2b(float f){
  union { float f; u32 i; } v; v.f = f;
  u32 x = v.i;
  return (u16)((x + 0x7fffu + ((x >> 16) & 1u)) >> 16);
}
// AUX cache policy (CPol): 0 = normal (read-only weights). 1 = SC0 (bypass L1,
// served by shared XCD L2 — valid because all exchange stores are SC1
// write-through, which keeps/makes the local L2 copy current). 16 = SC1 (L3).
template<int AUX>
__device__ __forceinline__ void g2l16(const void* g, void* l){
  __builtin_amdgcn_global_load_lds((const __attribute__((address_space(1))) u32*)g,
                                   (__attribute__((address_space(3))) u32*)l, 16, 0, AUX);
}
// device-coherent exchange stores (unchanged from passing kernel)
__device__ __forceinline__ void st_devf(float* p, float v){
  __hip_atomic_store(p, v, __ATOMIC_RELAXED, __HIP_MEMORY_SCOPE_AGENT);
}
__device__ __forceinline__ void stg16_sc(void* p, short8 v){
  asm volatile("global_store_dwordx4 %0, %1, off sc0 sc1" :: "v"(p), "v"(v) : "memory");
}
// volatile 16B load (prevents hoisting out of the step loop)
__device__ __forceinline__ short8 ldg16(const void* p){
  short8 r;
  asm volatile("global_load_dwordx4 %0, %1, off" : "=v"(r) : "v"(p) : "memory");
  return r;
}
__device__ __forceinline__ float ftanh(float x){
  float a = fabsf(x);
  float e = __expf(-2.f*a);
  float t = __fdividef(1.f - e, 1.f + e);
  return copysignf(t, x);
}
__device__ __forceinline__ void vwait(int n){
  switch(n){
    case 0: asm volatile("s_waitcnt vmcnt(0)" ::: "memory"); break;
    case 1: asm volatile("s_waitcnt vmcnt(1)" ::: "memory"); break;
    case 2: asm volatile("s_waitcnt vmcnt(2)" ::: "memory"); break;
    case 3: asm volatile("s_waitcnt vmcnt(3)" ::: "memory"); break;
    case 4: asm volatile("s_waitcnt vmcnt(4)" ::: "memory"); break;
    default: break;
  }
}

// RK45 (Dormand-Prince) b-coefficients
#define RB1 0.09114583333333333f
#define RB3 0.4492362982929021f
#define RB4 0.6510416666666666f
#define RB5 (-0.3223921568627451f)
#define RB6 0.13095238095238096f
#define MFMA16 __builtin_amdgcn_mfma_f32_16x16x32_bf16

/* ---------------- setup kernels ---------------- */

__global__ void zero_k(float* h, u16* h2, u32* bar){
  int i = blockIdx.x*256 + threadIdx.x;
  if (i < Bsz*Hsz) h[i] = 0.f;
  h2[i] = 0;
  if (i < 2304) bar[i] = 0u;   // flags [0..511], xcc ids [2048..2303]
}

__global__ void tsm_k(const float* tp, float* tsm){
  int s = blockIdx.x, tid = threadIdx.x;
  __shared__ float red[8];
  float v = tp[(size_t)tid*Ssz + s] + tp[(size_t)(tid + 256)*Ssz + s];
  int wave = tid >> 6, lane = tid & 63;
  for (int o = 32; o; o >>= 1) v += __shfl_down(v, o);
  if (!lane) red[wave] = v;
  __syncthreads();
  if (!tid) tsm[s] = (red[0] + red[1] + red[2] + red[3]) * (1.f/(512.f*72.f));
}

__global__ void sub_k(const float* tsm, float* subs){
  int i = threadIdx.x;
  if (i < Ssz){
    float dtm = (i == 0) ? 0.f : (tsm[i] - tsm[i-1]);
    float de = (dtm > 1e-4f) ? dtm : 0.f;
    subs[i] = de * 0.125f;
  }
}

__global__ void dti_k(const float* tp, float* dti){
  int i = blockIdx.x*256 + threadIdx.x;
  int ss = i & 127;
  dti[i] = ss ? (tp[i] - tp[i-1]) : 0.f;
}

__global__ void tr1_k(const float* w1, u16* lin, u16* swz){
  int i = blockIdx.x*256 + threadIdx.x;
  int n = i >> 9, k = i & 511;
  u16 v = f2b(w1[(size_t)k*NTWO + n]);
  lin[i] = v;
  swz[(size_t)n*512 + (k ^ ((n&7)<<3))] = v;
}

__global__ void cvt_k(const float* src, u16* dst, int n){
  int i = blockIdx.x*256 + threadIdx.x;
  if (i < n) dst[i] = f2b(src[i]);
}

__global__ void w2t_k(const float* w2, u16* dst){
  int i = blockIdx.x*256 + threadIdx.x;
  int n = i >> 10, k = i & 1023;
  dst[(size_t)n*1024 + (k ^ ((n&7)<<3))] = f2b(w2[(size_t)k*Hsz + n]);
}

__global__ void whh_k(const float* whh, u16* dst){
  int i = blockIdx.x*256 + threadIdx.x;
  int n = i >> 9, k = i & 511;
  dst[(size_t)n*512 + (k ^ ((n&7)<<3))] = f2b(whh[i]);
}

__global__ void wixs_k(const float* wih, u16* dst){
  int i = blockIdx.x*256 + threadIdx.x;
  int n = i >> 7, k = i & 127;
  dst[(size_t)n*128 + (k ^ ((n&7)<<3))] = f2b(wih[(size_t)n*129 + k]);
}

__global__ void wdt_k(const float* wih, float* wdt){
  int i = blockIdx.x*256 + threadIdx.x;
  if (i < 1536) wdt[i] = wih[(size_t)i*129 + 128];
}

__global__ void xsl_k(const float* vals, u16* dst){
  int i = blockIdx.x*256 + threadIdx.x;
  int p = i & 127;
  int b = (i >> 7) & 511;
  int s = i >> 16;
  int f = p ^ ((b&7)<<3);
  dst[i] = f2b(vals[((size_t)b*Ssz + s)*Fsz + f]);
}

__global__ void u_k(const float* b2v, const u16* w1t, float* u){
  int i = blockIdx.x*256 + threadIdx.x;
  if (i < NTWO){
    float acc = 0.f;
    for (int j = 0; j < Hsz; ++j) acc += b2v[j] * b2f(w1t[(size_t)i*Hsz + j]);
    u[i] = acc;
  }
}

/* --------- Gt = (w2@w1)^T setup GEMM (plain [n][k] output) --------- */
struct GArgs {
  const u16* A; const u16* Bt;
  int a_rs, b_rs, K, kmask;
  u16* GtOut;
};

__launch_bounds__(256)
__global__ void gemm_k(GArgs g){
  __shared__ __align__(16) u16 lA[2][64*64];
  __shared__ __align__(16) u16 lB[2][32*64];
  const int tid = threadIdx.x;
  const int wave = tid >> 6, lane = tid & 63;
  const int quad = lane >> 4, l16 = lane & 15;
  const int mb = blockIdx.x * 64;
  const int nb = blockIdx.y * 32;
  f32x4 acc0 = {0.f,0.f,0.f,0.f}, acc1 = {0.f,0.f,0.f,0.f};

  const int r0 = tid >> 3,         c0 = (tid & 7) ^ (r0 & 7);
  const int r1 = (256 + tid) >> 3, c1 = (tid & 7) ^ (r1 & 7);

  const int am = wave*16 + l16;
  const int aoff0 = am*64 + (((quad    ) ^ (am & 7)) << 3);
  const int aoff1 = am*64 + (((4 + quad) ^ (am & 7)) << 3);
  const int bn0 = l16, bn1 = 16 + l16;
  const int boff00 = bn0*64 + (((quad    ) ^ (bn0 & 7)) << 3);
  const int boff01 = bn0*64 + (((4 + quad) ^ (bn0 & 7)) << 3);
  const int boff10 = bn1*64 + (((quad    ) ^ (bn1 & 7)) << 3);
  const int boff11 = bn1*64 + (((4 + quad) ^ (bn1 & 7)) << 3);

  const int nkb = g.K >> 6;
  {
    g2l16<0>(g.A  + (size_t)(mb + r0) * g.a_rs + ((c0 << 3)),             &lA[0][tid << 3]);
    g2l16<0>(g.A  + (size_t)(mb + r1) * g.a_rs + ((c1 << 3)),             &lA[0][(256 + tid) << 3]);
    g2l16<0>(g.Bt + (size_t)(nb + r0) * g.b_rs + (((c0 << 3)) & g.kmask), &lB[0][tid << 3]);
  }
  __syncthreads();
  for (int kb = 0; kb < nkb; ++kb){
    int buf = kb & 1;
    if (kb + 1 < nkb){
      int k0 = (kb + 1) << 6, nbuf = buf ^ 1;
      g2l16<0>(g.A  + (size_t)(mb + r0) * g.a_rs + (k0 + (c0 << 3)),             &lA[nbuf][tid << 3]);
      g2l16<0>(g.A  + (size_t)(mb + r1) * g.a_rs + (k0 + (c1 << 3)),             &lA[nbuf][(256 + tid) << 3]);
      g2l16<0>(g.Bt + (size_t)(nb + r0) * g.b_rs + ((k0 + (c0 << 3)) & g.kmask), &lB[nbuf][tid << 3]);
    }
    short8 a0  = *(const short8*)&lA[buf][aoff0];
    short8 a1  = *(const short8*)&lA[buf][aoff1];
    short8 b00 = *(const short8*)&lB[buf][boff00];
    short8 b01 = *(const short8*)&lB[buf][boff01];
    short8 b10 = *(const short8*)&lB[buf][boff10];
    short8 b11 = *(const short8*)&lB[buf][boff11];
    acc0 = MFMA16(a0, b00, acc0, 0, 0, 0);
    acc0 = MFMA16(a1, b01, acc0, 0, 0, 0);
    acc1 = MFMA16(a0, b10, acc1, 0, 0, 0);
    acc1 = MFMA16(a1, b11, acc1, 0, 0, 0);
    __syncthreads();
  }
  #pragma unroll
  for (int cb = 0; cb < 2; ++cb){
    f32x4 a = cb ? acc1 : acc0;
    int n = nb + cb*16 + l16;
    #pragma unroll
    for (int r = 0; r < 4; ++r){
      int m = mb + wave*16 + quad*4 + r;
      g.GtOut[(size_t)m*NTWO + n] = f2b(a[r]);
    }
  }
}

/* ---------------- fused persistent kernel ---------------- */

struct FArgs {
  const u16 *Gt, *w1t, *w2t, *whh, *wix, *xs;
  u16 *t, *Ta, *h2;           // t double-buffered
  float *h, *GI, *GH, *out;
  const float *subs, *dti, *u, *b1, *b2, *bhh, *bih, *wdt, *gamma, *beta;
  u32 *bar;  // [0..511] flags (16 u32/group); [2048..2303] xcc ids
};

struct Sh {
  __align__(16) u16 sAfull[16*1024];   // 32 KB A slab (linear or chunk-major)
  __align__(16) u16 sBring[3][8192];   // 48 KB B ring / GI-B / staging
  __align__(16) u16 sTpack[2][2048];   // 8 KB pack tiles
  __align__(16) float sRed[1024];      // 4 KB K-split reduce / detect scratch
  float sLN[16];
  int mode;
};

// AUXD: load policy for cross-block exchange data (1 = XCD-L2 fast path,
// 16 = L3 device path). Stores/flags are identical in both modes.
template<int AUXD>
__device__ __forceinline__ void run_body(const FArgs& f, Sh& S, const int tid, const int bid){
  const int wave = tid >> 6, lane = tid & 63;
  const int quad = (lane >> 4) & 3, l16 = lane & 15;
  const int l7 = l16 & 7;
  const int g   = bid & 31;
  const int jb  = bid >> 5;
  const int r0  = g * 16;
  const int cb0 = jb * 128;
  const int wcol = wave*16 + l16;
  const int cw4 = (wave & 3)*16 + l16;

  u32* flagp = f.bar + g*16;
  u32 epA = 1, epW = 0;
  u16* sBflat = &S.sBring[0][0];

  const int   pcol = cb0 + wcol;
  const float uuv = f.u[pcol], bb1v = f.b1[pcol];
  const int   fcol = jb*64 + cw4;
  const float b2v = f.b2[fcol];
  const int   gcol1 = jb*192 + wcol;
  const int   gcol2 = jb*192 + 128 + cw4;
  const float bhh1 = f.bhh[gcol1], bih1 = f.bih[gcol1], wdt1 = f.wdt[gcol1];
  const float bhh2 = f.bhh[gcol2], bih2 = f.bih[gcol2], wdt2 = f.wdt[gcol2];
  const int   b0row = r0 + jb*2;
  const int   j0 = tid & 255, grow = tid >> 8;
  const float gmA = f.gamma[j0], gmB = f.gamma[j0+256];
  const float btA = f.beta[j0],  btB = f.beta[j0+256];
  const size_t TSZ = (size_t)Bsz*NTWO;

  if (tid == 0)
    __hip_atomic_store(&flagp[jb], 1u, __ATOMIC_RELAXED, __HIP_MEMORY_SCOPE_AGENT);

  auto arrive = [&](){
    ++epA;
    if (tid == 0)
      __hip_atomic_store(&flagp[jb], epA, __ATOMIC_RELAXED, __HIP_MEMORY_SCOPE_AGENT);
  };
  auto waitall = [&](){
    ++epW;
    if (wave == 0){
      for (;;){
        u32 fv = (lane < 8)
          ? __hip_atomic_load(&flagp[lane], __ATOMIC_RELAXED, __HIP_MEMORY_SCOPE_AGENT)
          : 0xFFFFFFFFu;
        if (__all(fv >= epW)) break;
        __builtin_amdgcn_s_sleep(1);
      }
    }
    __syncthreads();
  };

  // linear A staging (p/finish/GH phases): LDS[row][k8]
  auto stageA16 = [&](const u16* gsrc){
    #pragma unroll
    for (int i = 0; i < 4; ++i){
      int u = tid + i*512; int row = u >> 7; int k8 = u & 127;
      g2l16<AUXD>(gsrc + (((size_t)(r0+row)) << 10) + (k8 << 3), &S.sAfull[u << 3]);
    }
  };
  auto stageB2 = [&](const u16* gB, int burow, int bc, int slot){
    #pragma unroll
    for (int i = 0; i < 2; ++i){
      int u = tid + i*512; int col = u >> 3; int k8 = u & 7;
      g2l16<0>(gB + (size_t)col*(burow<<3) + (bc<<6) + (k8<<3), &S.sBring[slot][u << 3]);
    }
  };
  auto stageB1 = [&](const u16* gB, int burow, int bc, int slot){
    int col = tid >> 3; int k8 = tid & 7;
    g2l16<0>(gB + (size_t)col*(burow<<3) + (bc<<6) + (k8<<3), &S.sBring[slot][tid << 3]);
  };
  auto afrag = [&](int c, int kk)->short8 {
    return *(const short8*)&S.sAfull[(l16<<10) + (((c*8 + kk*4 + quad) ^ l7)<<3)];
  };
  auto bfragW = [&](int slot, int kk)->short8 {
    return *(const short8*)&S.sBring[slot][(wcol<<6) + ((((kk<<2)+quad) ^ (wcol&7))<<3)];
  };
  auto bfrag4 = [&](int slot, int kk)->short8 {
    return *(const short8*)&S.sBring[slot][(cw4<<6) + ((((kk<<2)+quad) ^ (cw4&7))<<3)];
  };

  f32x4 p_, T_, q0, q1, q2, q3, q4;
  short8 bfr[32];

  // ODE stage GEMM: chunk-major staging + counted-vmcnt pipeline.
  // LDS layout: [chunk c][row][k8o], chunk = 64 k (8 units of 8 bf16).
  auto ode_stage = [&](const u16* tb, f32x4& aA, f32x4& aB){
    #pragma unroll
    for (int i = 0; i < 4; ++i){
      int c = i*4 + (tid>>7);           // chunk 0..15
      int uu = tid & 127;
      int row = uu >> 3, k8o = uu & 7;
      g2l16<AUXD>(tb + (((size_t)(r0+row))<<10) + ((size_t)((c<<3)+k8o)<<3),
                  &S.sAfull[(c<<10) + (uu<<3)]);
    }
    #pragma unroll
    for (int ci = 0; ci < 4; ++ci){
      vwait(3-ci);
      __builtin_amdgcn_s_barrier();
      #pragma unroll
      for (int cc = ci*4; cc < ci*4+4; ++cc){
        short8 x0 = *(const short8*)&S.sAfull[(cc<<10) + (l16<<6) + (((quad    ) ^ l7)<<3)];
        short8 x1 = *(const short8*)&S.sAfull[(cc<<10) + (l16<<6) + (((4 + quad) ^ l7)<<3)];
        aA = MFMA16(x0, bfr[2*cc],   aA, 0,0,0);
        aB = MFMA16(x1, bfr[2*cc+1], aB, 0,0,0);
      }
    }
  };

  for (int s = 0; s < Ssz; ++s){
    const float sub = f.subs[s];
    const bool act = (sub > 0.f);   // uniform across all blocks

    waitall();  // h2/h ready from previous step's GRU (or initial)

    if (act){
      { // ---- p = h2@w1 + b1 ; t0 = tanh(p) ; T = sub*RB1*t ----
        stageA16(f.h2);
        const u16* wb = f.w1t + ((size_t)cb0)*512;
        stageB2(wb, 64, 0, 0); stageB2(wb, 64, 1, 1);
        f32x4 acc = {0.f,0.f,0.f,0.f};
        for (int c = 0; c < 16; ++c){
          vwait((c+1 < 16) ? 2 : 0);
          __builtin_amdgcn_s_barrier();
          if (c+2 < 16) stageB2(wb, 64, (c+2)&7, (c+2)%3);
          short8 a0 = afrag(c,0), a1 = afrag(c,1);
          short8 b0 = bfragW(c%3,0), b1 = bfragW(c%3,1);
          acc = MFMA16(a0, b0, acc, 0,0,0);
          acc = MFMA16(a1, b1, acc, 0,0,0);
        }
        __syncthreads();
        #pragma unroll
        for (int r = 0; r < 4; ++r){
          float v = acc[r] + bb1v; p_[r] = v;
          float tv = ftanh(v);     T_[r] = sub*RB1*tv;
          S.sTpack[0][(quad*4+r)*128 + wcol] = f2b(tv);
        }
        __syncthreads();
        if (tid < 256){
          int row = tid >> 4, c8 = tid & 15;
          short8 v = *(const short8*)&S.sTpack[0][tid << 3];
          stg16_sc(f.t + (((size_t)(r0+row))<<10) + ((size_t)((jb<<4) + (c8 ^ (row&7)))<<3), v);
        }
        vwait(0); __syncthreads();
        arrive();
      }

      // ---- load resident B-frags (Gt cols for this wave) ----
      {
        const u16* gtb = f.Gt + ((size_t)pcol << 10) + (quad << 3);
        #pragma unroll
        for (int cc = 0; cc < 32; ++cc) bfr[cc] = ldg16(gtb + cc*32);
        vwait(0);
      }

      // ---- 47 RK45 stage GEMMs ----
      int par = 0;
      for (int ssb = 0; ssb < 8; ++ssb){
        for (int st = 1; st <= 6; ++st){
          if (ssb == 7 && st == 6) break;
          const int wt = (ssb == 7 && st == 5) ? 1 : 0;
          waitall();
          f32x4 aA = {0.f,0.f,0.f,0.f}, aB = {0.f,0.f,0.f,0.f};
          ode_stage(f.t + (size_t)par*TSZ, aA, aB);
          #pragma unroll
          for (int r = 0; r < 4; ++r){
            float qv = aA[r] + aB[r] + uuv;
            float zs;
            if (st == 1){ q0[r] = qv; zs = 0.2f*qv; }
            else if (st == 2){ q1[r] = qv; zs = 0.075f*q0[r] + 0.225f*qv; }
            else if (st == 3){ q2[r] = qv;
              zs = (44.f/45.f)*q0[r] + (-56.f/15.f)*q1[r] + (32.f/9.f)*qv; }
            else if (st == 4){ q3[r] = qv;
              zs = 2.9525986892242035f*q0[r] + (-11.595793324188385f)*q1[r]
                 + 9.822892851699436f*q2[r] + (-0.2908093278463649f)*qv; }
            else if (st == 5){ q4[r] = qv;
              zs = 2.8462752525252526f*q0[r] + (-10.757575757575758f)*q1[r]
                 + 8.906422717743473f*q2[r] + 0.2784090909090909f*q3[r]
                 + (-0.2735313036020583f)*qv; }
            else {
              zs = RB1*q0[r] + RB3*q2[r] + RB4*q3[r] + RB5*q4[r] + RB6*qv;
            }
            float tv;
            if (st < 6){
              float z = p_[r] + sub*zs;
              tv = ftanh(z);
              if (st >= 2){
                float bn = (st == 2) ? RB3 : (st == 3) ? RB4 : (st == 4) ? RB5 : RB6;
                T_[r] += sub*bn*tv;
              }
            } else {
              p_[r] += sub*zs;
              tv = ftanh(p_[r]);
              T_[r] += sub*RB1*tv;
            }
            S.sTpack[0][(quad*4+r)*128 + wcol] = f2b(wt ? T_[r] : tv);
          }
          __syncthreads();
          if (tid < 256){
            int row = tid >> 4, c8 = tid & 15;
            short8 v = *(const short8*)&S.sTpack[0][tid << 3];
            u16* dst = wt ? f.Ta : (f.t + (size_t)(par^1)*TSZ);
            stg16_sc(dst + (((size_t)(r0+row))<<10) + ((size_t)((jb<<4) + (c8 ^ (row&7)))<<3), v);
          }
          vwait(0); __syncthreads();
          arrive();
          par ^= 1;
        }
      }

      { // ---- h += Ta@w2 + dt_eff*b2 ; h2 hi/lo ----
        waitall();
        stageA16(f.Ta);
        const u16* wb = f.w2t + ((size_t)(jb*64)) * 1024;
        stageB1(wb, 128, 0, 0); stageB1(wb, 128, 1, 1);
        f32x4 fa = {0.f,0.f,0.f,0.f};
        for (int c = 0; c < 16; ++c){
          vwait((c+1 < 16) ? 1 : 0);
          __builtin_amdgcn_s_barrier();
          if (c+2 < 16) stageB1(wb, 128, c+2, (c+2)%3);
          if ((c >> 3) == (wave >> 2)){
            short8 a0 = afrag(c,0), a1 = afrag(c,1);
            short8 b0 = bfrag4(c%3,0), b1 = bfrag4(c%3,1);
            fa = MFMA16(a0, b0, fa, 0,0,0);
            fa = MFMA16(a1, b1, fa, 0,0,0);
          }
        }
        __syncthreads();
        if (tid < 256){
          int row = tid >> 4, c4 = tid & 15;
          g2l16<AUXD>(f.h + (size_t)(r0+row)*512 + jb*64 + (c4<<2), &sBflat[tid << 3]);
        }
        if (wave >= 4){
          #pragma unroll
          for (int r = 0; r < 4; ++r)
            S.sRed[(wave&3)*256 + (quad*4+r)*16 + l16] = fa[r];
        }
        __syncthreads();
        if (wave < 4){
          vwait(0);
          const float* HS = (const float*)sBflat;
          #pragma unroll
          for (int r = 0; r < 4; ++r){
            int lrow = quad*4 + r;
            float hv = HS[lrow*64 + cw4] + fa[r] + S.sRed[(wave&3)*256 + lrow*16 + l16]
                     + 8.f*sub*b2v;
            st_devf(&f.h[(size_t)(r0+lrow)*512 + fcol], hv);
            u16 hi = f2b(hv);
            S.sTpack[0][lrow*64 + cw4] = hi;
            S.sTpack[0][1024 + lrow*64 + cw4] = f2b(hv - b2f(hi));
          }
        }
        __syncthreads();
        if (tid < 256){
          int half = tid >> 7, row = (tid >> 3) & 15, c8 = tid & 7;
          short8 v = *(const short8*)&S.sTpack[0][tid << 3];
          size_t gu = (((size_t)(r0+row)) << 7) + (half<<6) + (jb<<3) + (c8 ^ (row&7));
          stg16_sc(f.h2 + (gu << 3), v);
        }
        vwait(0); __syncthreads();
        arrive();
        waitall();   // h2 fully updated by all 8 blocks
      }
    }

    { // ---- GH = h2@whh^T + bhh ----
      stageA16(f.h2);
      const u16* wb1 = f.whh + ((size_t)(jb*192)) * 512;
      stageB2(wb1, 64, 0, 0); stageB2(wb1, 64, 1, 1);
      f32x4 gh = {0.f,0.f,0.f,0.f};
      for (int c = 0; c < 16; ++c){
        vwait((c+1 < 16) ? 2 : 0);
        __builtin_amdgcn_s_barrier();
        if (c+2 < 16) stageB2(wb1, 64, (c+2)&7, (c+2)%3);
        short8 a0 = afrag(c,0), a1 = afrag(c,1);
        short8 b0 = bfragW(c%3,0), b1 = bfragW(c%3,1);
        gh = MFMA16(a0, b0, gh, 0,0,0);
        gh = MFMA16(a1, b1, gh, 0,0,0);
      }
      #pragma unroll
      for (int r = 0; r < 4; ++r)
        st_devf(&f.GH[(size_t)(r0+quad*4+r)*1536 + gcol1], gh[r] + bhh1);
      __syncthreads();
      const u16* wb2 = f.whh + ((size_t)(jb*192+128)) * 512;
      stageB1(wb2, 64, 0, 0); stageB1(wb2, 64, 1, 1);
      f32x4 g2 = {0.f,0.f,0.f,0.f};
      for (int c = 0; c < 8; ++c){
        vwait((c+1 < 8) ? 1 : 0);
        __builtin_amdgcn_s_barrier();
        if (c+2 < 8) stageB1(wb2, 64, c+2, (c+2)%3);
        int ac = c + ((wave >= 4) ? 8 : 0);
        short8 a0 = afrag(ac,0), a1 = afrag(ac,1);
        short8 b0 = bfrag4(c%3,0), b1 = bfrag4(c%3,1);
        g2 = MFMA16(a0, b0, g2, 0,0,0);
        g2 = MFMA16(a1, b1, g2, 0,0,0);
      }
      __syncthreads();
      if (wave >= 4){
        #pragma unroll
        for (int r = 0; r < 4; ++r)
          S.sRed[(wave&3)*256 + (quad*4+r)*16 + l16] = g2[r];
      }
      __syncthreads();
      if (wave < 4){
        #pragma unroll
        for (int r = 0; r < 4; ++r){
          float v = g2[r] + S.sRed[wave*256 + (quad*4+r)*16 + l16];
          st_devf(&f.GH[(size_t)(r0+quad*4+r)*1536 + gcol2], v + bhh2);
        }
      }
      __syncthreads();
    }

    { // ---- GI = xs@wix^T + dti*wdt + bih ----
      if (tid < 256){
        int row = tid >> 4, k16 = tid & 15;
        g2l16<0>(f.xs + (((size_t)s*512 + r0 + row) << 7) + (k16 << 3), &S.sAfull[tid << 3]);
      }
      #pragma unroll
      for (int i = 0; i < 6; ++i){
        int u = tid + i*512; int col = u >> 4; int k16 = u & 15;
        g2l16<0>(f.wix + (((size_t)(jb*192 + col)) << 7) + (k16 << 3), &sBflat[u << 3]);
      }
      vwait(0); __syncthreads();
      f32x4 gi = {0.f,0.f,0.f,0.f};
      #pragma unroll
      for (int c = 0; c < 4; ++c){
        short8 a = *(const short8*)&S.sAfull[(l16<<7) + ((((c<<2)+quad) ^ l7)<<3)];
        short8 b = *(const short8*)&sBflat[(wcol<<7) + ((((c<<2)+quad) ^ (wcol&7))<<3)];
        gi = MFMA16(a, b, gi, 0,0,0);
      }
      #pragma unroll
      for (int r = 0; r < 4; ++r){
        float dv = f.dti[((size_t)(r0+quad*4+r) << 7) + s];
        st_devf(&f.GI[(size_t)(r0+quad*4+r)*1536 + gcol1], gi[r] + bih1 + dv*wdt1);
      }
      if (wave < 4){
        int cw2 = 128 + cw4;
        f32x4 gi2 = {0.f,0.f,0.f,0.f};
        #pragma unroll
        for (int c = 0; c < 4; ++c){
          short8 a = *(const short8*)&S.sAfull[(l16<<7) + ((((c<<2)+quad) ^ l7)<<3)];
          short8 b = *(const short8*)&sBflat[(cw2<<7) + ((((c<<2)+quad) ^ (cw2&7))<<3)];
          gi2 = MFMA16(a, b, gi2, 0,0,0);
        }
        #pragma unroll
        for (int r = 0; r < 4; ++r){
          float dv = f.dti[((size_t)(r0+quad*4+r) << 7) + s];
          st_devf(&f.GI[(size_t)(r0+quad*4+r)*1536 + gcol2], gi2[r] + bih2 + dv*wdt2);
        }
      }
      vwait(0); __syncthreads();
      arrive();
    }

    { // ---- GRU + LayerNorm (2 rows per block) ----
      waitall();
      #pragma unroll
      for (int i = 0; i < 4; ++i){
        int u = tid + i*512;
        if (u < 1792){
          const float* src;
          if (u < 768){ int row = (u >= 384); int off = u - row*384;
            src = f.GI + (size_t)(b0row+row)*1536 + (off<<2); }
          else if (u < 1536){ int v2 = u - 768; int row = (v2 >= 384); int off = v2 - row*384;
            src = f.GH + (size_t)(b0row+row)*1536 + (off<<2); }
          else { int v2 = u - 1536; int row = v2 >> 7; int off = v2 & 127;
            src = f.h + (size_t)(b0row+row)*512 + (off<<2); }
          g2l16<AUXD>(src, &S.sAfull[u << 3]);
        }
      }
      vwait(0); __syncthreads();
      const float* LSf = (const float*)S.sAfull;
      const float* GIr = LSf + grow*1536;
      const float* GHr = LSf + 3072 + grow*1536;
      const float* Hr  = LSf + 6144 + grow*512;
      float hn0, hn1;
      {
        float gr = GIr[j0] + GHr[j0];
        float gz = GIr[512 + j0] + GHr[512 + j0];
        float ng = ftanh(GIr[1024 + j0] + (1.f/(1.f + __expf(-gr)))*GHr[1024 + j0]);
        float zg = 1.f/(1.f + __expf(-gz));
        hn0 = (1.f - zg)*ng + zg*Hr[j0];
      }
      {
        int j = j0 + 256;
        float gr = GIr[j] + GHr[j];
        float gz = GIr[512 + j] + GHr[512 + j];
        float ng = ftanh(GIr[1024 + j] + (1.f/(1.f + __expf(-gr)))*GHr[1024 + j]);
        float zg = 1.f/(1.f + __expf(-gz));
        hn1 = (1.f - zg)*ng + zg*Hr[j];
      }
      st_devf(&f.h[(size_t)(b0row+grow)*512 + j0], hn0);
      st_devf(&f.h[(size_t)(b0row+grow)*512 + j0 + 256], hn1);
      u16* sT = &S.sTpack[0][0];
      u16 hi0 = f2b(hn0);
      sT[grow*1024 + j0]       = hi0;
      sT[grow*1024 + 512 + j0] = f2b(hn0 - b2f(hi0));
      u16 hi1 = f2b(hn1);
      sT[grow*1024 + 256 + j0] = hi1;
      sT[grow*1024 + 768 + j0] = f2b(hn1 - b2f(hi1));
      float sm = hn0 + hn1;
      for (int o = 32; o; o >>= 1) sm += __shfl_down(sm, o);
      if (!lane) S.sLN[wave] = sm;
      __syncthreads();
      if (tid == 0 || tid == 256){
        int rr = tid >> 8;
        S.sLN[8+rr] = (S.sLN[rr*4]+S.sLN[rr*4+1]+S.sLN[rr*4+2]+S.sLN[rr*4+3]) * (1.f/512.f);
      }
      __syncthreads();
      float mu = S.sLN[8+grow];
      float d0 = hn0 - mu, d1 = hn1 - mu;
      float ss = d0*d0 + d1*d1;
      for (int o = 32; o; o >>= 1) ss += __shfl_down(ss, o);
      if (!lane) S.sLN[wave] = ss;
      __syncthreads();
      if (tid == 0 || tid == 256){
        int rr = tid >> 8;
        S.sLN[12+rr] = rsqrtf((S.sLN[rr*4]+S.sLN[rr*4+1]+S.sLN[rr*4+2]+S.sLN[rr*4+3]) * (1.f/512.f) + 1e-5f);
      }
      __syncthreads();
      float isd = S.sLN[12+grow];
      size_t ob = ((size_t)(b0row+grow)*128 + s)*512;
      f.out[ob + j0]       = d0*isd*gmA + btA;
      f.out[ob + j0 + 256] = d1*isd*gmB + btB;
      __syncthreads();
      if (tid < 256){
        int row = tid >> 7, u8 = tid & 127;
        int b = b0row + row;
        short8 v = *(const short8*)&sT[(row*128 + u8) << 3];
        stg16_sc(f.h2 + (((size_t)b) << 10) + ((size_t)(u8 ^ (b&7)) << 3), v);
      }
      vwait(0); __syncthreads();
      arrive();
    }
  }
}

__launch_bounds__(512, 2)
__global__ void fused_k(FArgs f){
  __shared__ Sh S;
  const int tid = threadIdx.x, bid = blockIdx.x;
  const int g = bid & 31;
  // ---- one-time XCD co-residency detection (builtin getreg + histogram) ----
  {
    u32* xa = f.bar + 2048;
    if (tid == 0){
      // s_getreg(HW_REG_XCC_ID): simm16 = id 20 | size-1 (31) << 11 = 63508.
      u32 xcc = ((u32)__builtin_amdgcn_s_getreg(63508) & 0xFu) + 1u;
      __hip_atomic_store(&xa[bid], xcc, __ATOMIC_RELAXED, __HIP_MEMORY_SCOPE_AGENT);
    }
    if (tid < 256){
      u32 v;
      do {
        v = __hip_atomic_load(&xa[tid], __ATOMIC_RELAXED, __HIP_MEMORY_SCOPE_AGENT);
        if (!v) __builtin_amdgcn_s_sleep(4);
      } while (!v);
      ((u32*)S.sRed)[tid] = v;
    }
    __syncthreads();
    if (tid == 0){
      const u32* xv = (const u32*)S.sRed;
      u32 v0 = xv[g];
      int eq = 1;
      for (int j = 1; j < 8; ++j) eq &= (xv[g + 32*j] == v0);
      int cnt = 0;
      for (int i = 0; i < 256; ++i) cnt += (xv[i] == v0);
      // fast path only when the 8 group members share a value held by exactly
      // one XCD-sized set of blocks (32). Any getreg garbage fails this.
      S.mode = (eq && cnt == 32) ? 1 : 0;
    }
    __syncthreads();
  }
  if (S.mode) run_body<1>(f, S, tid, bid);
  else        run_body<16>(f, S, tid, bid);
}

/* ---------------- launcher ---------------- */

extern "C" void kernel_launch(void* const* d_in, const int* in_sizes, int n_in,
                              void* d_out, int out_size, void* d_ws, size_t ws_size,
                              hipStream_t stream){
  (void)in_sizes; (void)n_in; (void)out_size; (void)ws_size;
  const float* tp    = (const float*)d_in[0];
  const float* vals  = (const float*)d_in[1];
  const float* w1    = (const float*)d_in[2];
  const float* b1v   = (const float*)d_in[3];
  const float* w2    = (const float*)d_in[4];
  const float* b2v   = (const float*)d_in[5];
  const float* wih   = (const float*)d_in[6];
  const float* whh   = (const float*)d_in[7];
  const float* bih   = (const float*)d_in[8];
  const float* bhh   = (const float*)d_in[9];
  const float* gamma = (const float*)d_in[10];
  const float* beta  = (const float*)d_in[11];
  float* out = (float*)d_out;

  uint8_t* w = (uint8_t*)d_ws;
  size_t off = 0;
  auto alloc = [&](size_t bytes)->void*{
    void* pp = w + off; off += (bytes + 255) & ~(size_t)255; return pp; };
  float* h      = (float*)alloc((size_t)Bsz*Hsz*4);
  u16*   h2     = (u16*)alloc((size_t)Bsz*NTWO*2);
  u16*   tbuf   = (u16*)alloc((size_t)2*Bsz*NTWO*2);
  u16*   Ta     = (u16*)alloc((size_t)Bsz*NTWO*2);
  float* GH     = (float*)alloc((size_t)Bsz*1536*4);
  float* GI     = (float*)alloc((size_t)Bsz*1536*4);
  u16*   Gt     = (u16*)alloc((size_t)NTWO*NTWO*2);
  u16*   w1tl   = (u16*)alloc((size_t)NTWO*Hsz*2);
  u16*   w1ts   = (u16*)alloc((size_t)NTWO*Hsz*2);
  u16*   w2bf   = (u16*)alloc((size_t)NTWO*Hsz*2);
  u16*   w2ts   = (u16*)alloc((size_t)Hsz*NTWO*2);
  u16*   whhs   = (u16*)alloc((size_t)1536*Hsz*2);
  u16*   wixs   = (u16*)alloc((size_t)1536*128*2);
  u16*   xs     = (u16*)alloc((size_t)Ssz*Bsz*Fsz*2);
  float* wdt    = (float*)alloc(1536*4);
  float* uvec   = (float*)alloc(NTWO*4);
  float* tsm    = (float*)alloc(Ssz*4);
  float* subs   = (float*)alloc(Ssz*4);
  float* dti    = (float*)alloc((size_t)Bsz*Ssz*4);
  u32*   bar    = (u32*)alloc(16384);

  hipLaunchKernelGGL(zero_k, dim3(2048), dim3(256), 0, stream, h, h2, bar);
  hipLaunchKernelGGL(tsm_k,  dim3(128),  dim3(256), 0, stream, tp, tsm);
  hipLaunchKernelGGL(sub_k,  dim3(1),    dim3(128), 0, stream, tsm, subs);
  hipLaunchKernelGGL(dti_k,  dim3(256),  dim3(256), 0, stream, tp, dti);
  hipLaunchKernelGGL(tr1_k,  dim3(2048), dim3(256), 0, stream, w1, w1tl, w1ts);
  hipLaunchKernelGGL(cvt_k,  dim3(2048), dim3(256), 0, stream, w2, w2bf, NTWO*Hsz);
  hipLaunchKernelGGL(w2t_k,  dim3(2048), dim3(256), 0, stream, w2, w2ts);
  hipLaunchKernelGGL(whh_k,  dim3(3072), dim3(256), 0, stream, whh, whhs);
  hipLaunchKernelGGL(wixs_k, dim3(768),  dim3(256), 0, stream, wih, wixs);
  hipLaunchKernelGGL(wdt_k,  dim3(6),    dim3(256), 0, stream, wih, wdt);
  hipLaunchKernelGGL(xsl_k,  dim3(32768),dim3(256), 0, stream, vals, xs);
  hipLaunchKernelGGL(u_k,    dim3(4),    dim3(256), 0, stream, b2v, w1tl, uvec);
  {
    GArgs g{};
    g.A = w1tl; g.Bt = w2bf; g.a_rs = Hsz; g.b_rs = Hsz; g.K = Hsz;
    g.kmask = 511; g.GtOut = Gt;
    hipLaunchKernelGGL(gemm_k, dim3(16,32), dim3(256), 0, stream, g);
  }

  FArgs fa{};
  fa.Gt = Gt; fa.w1t = w1ts; fa.w2t = w2ts; fa.whh = whhs; fa.wix = wixs; fa.xs = xs;
  fa.t = tbuf; fa.Ta = Ta; fa.h2 = h2;
  fa.h = h; fa.GI = GI; fa.GH = GH; fa.out = out;
  fa.subs = subs; fa.dti = dti; fa.u = uvec; fa.b1 = b1v; fa.b2 = b2v;
  fa.bhh = bhh; fa.bih = bih; fa.wdt = wdt; fa.gamma = gamma; fa.beta = beta;
  fa.bar = bar;

  void* params[] = { (void*)&fa };
  hipError_t e = hipLaunchCooperativeKernel((const void*)fused_k, dim3(256), dim3(512),
                                            params, 0u, stream);
  if (e != hipSuccess){
    hipLaunchKernelGGL(fused_k, dim3(256), dim3(512), 0, stream, fa);
  }
}